// Round 5
// baseline (218.017 us; speedup 1.0000x reference)
//
#include <hip/hip_runtime.h>

typedef unsigned short u16;
typedef unsigned int   u32;
typedef short bf16x8 __attribute__((ext_vector_type(8)));
typedef float f32x4  __attribute__((ext_vector_type(4)));

__device__ __forceinline__ u16 f2bf(float f) {
  union { float f; u32 u; } v; v.f = f;
  u32 u = v.u;
  u += 0x7fffu + ((u >> 16) & 1u);   // RNE
  return (u16)(u >> 16);
}

__device__ __forceinline__ void splitbf(float x, u16& hi, u16& lo) {
  hi = f2bf(x);
  union { u32 u; float f; } r; r.u = (u32)hi << 16;
  lo = f2bf(x - r.f);
}

__device__ __forceinline__ float bflo(u32 p) {
  union { u32 u; float f; } v; v.u = p << 16; return v.f;
}
__device__ __forceinline__ float bfhi(u32 p) {
  union { u32 u; float f; } v; v.u = p & 0xffff0000u; return v.f;
}
__device__ __forceinline__ u32 cvtpk(float lo, float hi) {
  u32 r;
  asm("v_cvt_pk_bf16_f32 %0, %1, %2" : "=v"(r) : "v"(lo), "v"(hi));
  return r;
}
__device__ __forceinline__ void gload_lds16(const void* src, void* dst) {
  __builtin_amdgcn_global_load_lds(
      (const __attribute__((address_space(1))) u32*)src,
      (__attribute__((address_space(3))) u32*)dst, 16, 0, 0);
}

// ---------------------------------------------------------------------------
// k_prepT: LDS-tile transpose of the big layer-1 weights.
//  task 0..2: {mW1, pW1a, pW1b} [2304][150] -> Wcath/l [480][2304] (split bf16)
//  task 3   : aW1 [768][150]    -> aW1Th/l [160][768]
//  task 4   : pW1c [2304][150]  -> Wckg [288 grp][160 h][8 s] bf16
// ---------------------------------------------------------------------------
__global__ __launch_bounds__(256) void k_prepT(
    const float* __restrict__ mW1, const float* __restrict__ pW1,
    const float* __restrict__ aW1,
    u16* __restrict__ Wcath, u16* __restrict__ Wcatl,
    u16* __restrict__ aW1Th, u16* __restrict__ aW1Tl,
    u16* __restrict__ Wckg) {
  __shared__ float ls[64][153];
  const int tid = threadIdx.x;
  const int task = blockIdx.y;
  const int e0 = blockIdx.x * 64;
  if (task == 3 && e0 >= 768) return;
  const float* src;
  if (task == 0)      src = mW1;
  else if (task == 1) src = pW1;
  else if (task == 2) src = pW1 + (size_t)2304 * 150;
  else if (task == 3) src = aW1;
  else                src = pW1 + (size_t)4608 * 150;
  for (int t = tid; t < 9600; t += 256) {
    int r = t / 150, c = t - r * 150;
    ls[r][c] = src[(size_t)(e0 + r) * 150 + c];
  }
  __syncthreads();
  if (task < 3) {
    u16* dh = Wcath + (size_t)task * 160 * 2304;
    u16* dl = Wcatl + (size_t)task * 160 * 2304;
    for (int t = tid; t < 10240; t += 256) {
      int n = t >> 6, r = t & 63;
      float v = (n < 150) ? ls[r][n] : 0.f;
      u16 h, l; splitbf(v, h, l);
      dh[(size_t)n * 2304 + e0 + r] = h;
      dl[(size_t)n * 2304 + e0 + r] = l;
    }
  } else if (task == 3) {
    for (int t = tid; t < 10240; t += 256) {
      int n = t >> 6, r = t & 63;
      float v = (n < 150) ? ls[r][n] : 0.f;
      u16 h, l; splitbf(v, h, l);
      aW1Th[(size_t)n * 768 + e0 + r] = h;
      aW1Tl[(size_t)n * 768 + e0 + r] = l;
    }
  } else {
    for (int t = tid; t < 10240; t += 256) {
      int n = t >> 6, r = t & 63;
      int e = e0 + r;
      float v = (n < 150) ? ls[r][n] : 0.f;
      Wckg[((size_t)(e >> 3) * 160 + n) * 8 + (e & 7)] = f2bf(v);
    }
  }
}

// ---------------------------------------------------------------------------
// k_prep0: small padded layouts.
// ---------------------------------------------------------------------------
__global__ __launch_bounds__(256) void k_prep0(
    const float* __restrict__ aW2, const float* __restrict__ mW2,
    const float* __restrict__ pW2, const float* __restrict__ pb1,
    const float* __restrict__ pb2, const float* __restrict__ pW3,
    float* __restrict__ aW2p, float* __restrict__ mW2p,
    u16* __restrict__ W2kg, float* __restrict__ pb1p,
    float* __restrict__ pb2p, float* __restrict__ w3p) {
  const int stride = gridDim.x * blockDim.x;
  const int t0 = blockIdx.x * blockDim.x + threadIdx.x;
  for (int t = t0; t < 152*160; t += stride) {
    int k = t / 160, h = t % 160;
    bool ok = (k < 150 && h < 150);
    aW2p[t] = ok ? aW2[k*150 + h] : 0.f;
    mW2p[t] = ok ? mW2[k*150 + h] : 0.f;
  }
  for (int t = t0; t < 24*1280; t += stride) {
    int kg = t / 1280, rem = t % 1280;
    int s = rem / 160, n = rem % 160;
    int k = kg*8 + s;
    float v = (k < 150 && n < 150) ? pW2[k*150 + n] : 0.f;
    W2kg[(size_t)kg*1280 + n*8 + s] = f2bf(v);
  }
  for (int t = t0; t < 160; t += stride) {
    pb1p[t] = (t < 150) ? pb1[t] : 0.f;
    pb2p[t] = (t < 150) ? pb2[t] : 0.f;
    w3p[t]  = (t < 150) ? pW3[t] : 0.f;
  }
}

// ---------------------------------------------------------------------------
// attn layer1 (split-bf16 MFMA GEMM, split-K x2): raw partials
// ---------------------------------------------------------------------------
__global__ __launch_bounds__(256) void k_attn1(
    const float* __restrict__ e, const u16* __restrict__ Wh,
    const u16* __restrict__ Wl, float* __restrict__ h1p) {
  __shared__ u16 lXh[32*64], lXl[32*64], lWh[160*64], lWl[160*64];
  const int tid = threadIdx.x, lane = tid & 63, w = tid >> 6;
  const int wm = w & 1, wh = w >> 1;
  const int m0 = blockIdx.x * 32;
  const int z  = blockIdx.y;
  f32x4 acc[5] = {};
  for (int e0 = z*384; e0 < (z+1)*384; e0 += 64) {
    {
      int r = tid >> 3, ec = tid & 7;
      const float* src = e + (size_t)(m0 + r)*768 + e0 + ec*8;
      float4 x0 = *(const float4*)src, x1 = *(const float4*)(src + 4);
      float xs[8] = {x0.x,x0.y,x0.z,x0.w,x1.x,x1.y,x1.z,x1.w};
      u16 hb[8], lb[8];
#pragma unroll
      for (int q = 0; q < 8; ++q) splitbf(xs[q], hb[q], lb[q]);
      int off = (r*128 + ec*16) ^ ((r & 7) << 4);
      *(uint4*)((char*)lXh + off) = make_uint4(
        (u32)hb[0]|((u32)hb[1]<<16), (u32)hb[2]|((u32)hb[3]<<16),
        (u32)hb[4]|((u32)hb[5]<<16), (u32)hb[6]|((u32)hb[7]<<16));
      *(uint4*)((char*)lXl + off) = make_uint4(
        (u32)lb[0]|((u32)lb[1]<<16), (u32)lb[2]|((u32)lb[3]<<16),
        (u32)lb[4]|((u32)lb[5]<<16), (u32)lb[6]|((u32)lb[7]<<16));
    }
#pragma unroll
    for (int t = 0; t < 5; ++t) {
      int c = tid + t*256;
      int h = c >> 3, ec = c & 7;
      int off = (h*128 + ec*16) ^ ((h & 7) << 4);
      *(uint4*)((char*)lWh + off) = *(const uint4*)(Wh + (size_t)h*768 + e0 + ec*8);
      *(uint4*)((char*)lWl + off) = *(const uint4*)(Wl + (size_t)h*768 + e0 + ec*8);
    }
    __syncthreads();
#pragma unroll
    for (int ks = 0; ks < 2; ++ks) {
      int eb = ks*64 + ((lane >> 4) << 4);
      int ar = wm*16 + (lane & 15);
      bf16x8 Ah = *(const bf16x8*)((const char*)lXh + ((ar*128 + eb) ^ ((ar & 7) << 4)));
      bf16x8 Al = *(const bf16x8*)((const char*)lXl + ((ar*128 + eb) ^ ((ar & 7) << 4)));
#pragma unroll
      for (int t = 0; t < 5; ++t) {
        int br = wh*80 + t*16 + (lane & 15);
        bf16x8 Bh = *(const bf16x8*)((const char*)lWh + ((br*128 + eb) ^ ((br & 7) << 4)));
        bf16x8 Bl = *(const bf16x8*)((const char*)lWl + ((br*128 + eb) ^ ((br & 7) << 4)));
        acc[t] = __builtin_amdgcn_mfma_f32_16x16x32_bf16(Ah, Bh, acc[t], 0, 0, 0);
        acc[t] = __builtin_amdgcn_mfma_f32_16x16x32_bf16(Al, Bh, acc[t], 0, 0, 0);
        acc[t] = __builtin_amdgcn_mfma_f32_16x16x32_bf16(Ah, Bl, acc[t], 0, 0, 0);
      }
    }
    __syncthreads();
  }
#pragma unroll
  for (int t = 0; t < 5; ++t) {
    int n = wh*80 + t*16 + (lane & 15);
#pragma unroll
    for (int r = 0; r < 4; ++r) {
      int m = m0 + wm*16 + ((lane >> 4) << 2) + r;
      h1p[((size_t)z*2048 + m)*160 + n] = acc[t][r];
    }
  }
}

// ---------------------------------------------------------------------------
// attn layers 2+3 (sums split-K partials, bias+relu, then MLP tail)
// ---------------------------------------------------------------------------
__global__ __launch_bounds__(256) void k_attn2(
    const float* __restrict__ h1p, const float* __restrict__ W2p,
    const float* __restrict__ b1, const float* __restrict__ b2,
    const float* __restrict__ w3, const float* __restrict__ b3,
    float* __restrict__ attn) {
  __shared__ float hs[8][160];
  const int tid = threadIdx.x;
  const int t0 = blockIdx.x * 8;
  for (int idx = tid; idx < 1280; idx += 256) {
    int m = idx / 160, h = idx - m * 160;
    float s = h1p[(size_t)(t0 + m)*160 + h] + h1p[(size_t)(2048 + t0 + m)*160 + h];
    hs[m][h] = (h < 150) ? fmaxf(s + b1[h], 0.f) : 0.f;
  }
  __syncthreads();
  const int sp = tid >> 5, hb = tid & 31;
  float a2[5] = {0.f,0.f,0.f,0.f,0.f};
  for (int k = 0; k < 150; ++k) {
    float x = hs[sp][k];
#pragma unroll
    for (int q = 0; q < 5; ++q) a2[q] = fmaf(x, W2p[k*160 + hb + 32*q], a2[q]);
  }
  float p = 0.f;
#pragma unroll
  for (int q = 0; q < 5; ++q) {
    int h = hb + 32*q;
    if (h < 150) p += fmaxf(a2[q] + b2[h], 0.f) * w3[h];
  }
  p += __shfl_xor(p, 16, 32);
  p += __shfl_xor(p, 8, 32);
  p += __shfl_xor(p, 4, 32);
  p += __shfl_xor(p, 2, 32);
  p += __shfl_xor(p, 1, 32);
  if (hb == 0) attn[t0 + sp] = p + b3[0];
}

// ---------------------------------------------------------------------------
// g[s] = [e[start], e[end], span_sum]; also writes gkg (k-grouped bf16)
// ---------------------------------------------------------------------------
__global__ __launch_bounds__(256) void k_spans(
    const float* __restrict__ e, const float* __restrict__ attn,
    const int* __restrict__ sstart, const int* __restrict__ swidth,
    float* __restrict__ g, u16* __restrict__ gkg) {
  const int s = blockIdx.x;
  int st = sstart[s];
  int en = st + swidth[s];
  if (en > 2047) en = 2047;
  if (en < 0) en = 0;
  const int tid = threadIdx.x;
  for (int d = tid; d < 768; d += 256) {
    float v0 = e[(size_t)st*768 + d];
    float v1 = e[(size_t)en*768 + d];
    float acc = 0.f;
    for (int t = st; t <= en; ++t) acc += e[(size_t)t*768 + d] * attn[t];
    g[s*2304 + d]        = v0;
    g[s*2304 + 768 + d]  = v1;
    g[s*2304 + 1536 + d] = acc;
    int c0 = d, c1 = 768 + d, c2 = 1536 + d;
    gkg[((size_t)(c0>>3)*256 + s)*8 + (c0&7)] = f2bf(v0);
    gkg[((size_t)(c1>>3)*256 + s)*8 + (c1&7)] = f2bf(v1);
    gkg[((size_t)(c2>>3)*256 + s)*8 + (c2&7)] = f2bf(acc);
  }
}

// ---------------------------------------------------------------------------
// span layer1 (split-bf16 MFMA GEMM, split-K x4): raw partials
// ---------------------------------------------------------------------------
__global__ __launch_bounds__(128) void k_span1(
    const float* __restrict__ g, const u16* __restrict__ Wh,
    const u16* __restrict__ Wl, float* __restrict__ pp) {
  __shared__ u16 lXh[16*64], lXl[16*64], lWh[160*64], lWl[160*64];
  const int tid = threadIdx.x, lane = tid & 63;
  const int wh = tid >> 6;
  const int m0 = blockIdx.x * 16;
  const int n0 = blockIdx.y * 160;
  const int z  = blockIdx.z;
  f32x4 acc[5] = {};
  for (int e0 = z*576; e0 < (z+1)*576; e0 += 64) {
    {
      int r = tid >> 3, ec = tid & 7;
      const float* src = g + (size_t)(m0 + r)*2304 + e0 + ec*8;
      float4 x0 = *(const float4*)src, x1 = *(const float4*)(src + 4);
      float xs[8] = {x0.x,x0.y,x0.z,x0.w,x1.x,x1.y,x1.z,x1.w};
      u16 hb[8], lb[8];
#pragma unroll
      for (int q = 0; q < 8; ++q) splitbf(xs[q], hb[q], lb[q]);
      int off = (r*128 + ec*16) ^ ((r & 7) << 4);
      *(uint4*)((char*)lXh + off) = make_uint4(
        (u32)hb[0]|((u32)hb[1]<<16), (u32)hb[2]|((u32)hb[3]<<16),
        (u32)hb[4]|((u32)hb[5]<<16), (u32)hb[6]|((u32)hb[7]<<16));
      *(uint4*)((char*)lXl + off) = make_uint4(
        (u32)lb[0]|((u32)lb[1]<<16), (u32)lb[2]|((u32)lb[3]<<16),
        (u32)lb[4]|((u32)lb[5]<<16), (u32)lb[6]|((u32)lb[7]<<16));
    }
#pragma unroll
    for (int t = 0; t < 10; ++t) {
      int c = tid + t*128;
      int h = c >> 3, ec = c & 7;
      int off = (h*128 + ec*16) ^ ((h & 7) << 4);
      *(uint4*)((char*)lWh + off) = *(const uint4*)(Wh + (size_t)(n0 + h)*2304 + e0 + ec*8);
      *(uint4*)((char*)lWl + off) = *(const uint4*)(Wl + (size_t)(n0 + h)*2304 + e0 + ec*8);
    }
    __syncthreads();
#pragma unroll
    for (int ks = 0; ks < 2; ++ks) {
      int eb = ks*64 + ((lane >> 4) << 4);
      int ar = lane & 15;
      bf16x8 Ah = *(const bf16x8*)((const char*)lXh + ((ar*128 + eb) ^ ((ar & 7) << 4)));
      bf16x8 Al = *(const bf16x8*)((const char*)lXl + ((ar*128 + eb) ^ ((ar & 7) << 4)));
#pragma unroll
      for (int t = 0; t < 5; ++t) {
        int br = wh*80 + t*16 + (lane & 15);
        bf16x8 Bh = *(const bf16x8*)((const char*)lWh + ((br*128 + eb) ^ ((br & 7) << 4)));
        bf16x8 Bl = *(const bf16x8*)((const char*)lWl + ((br*128 + eb) ^ ((br & 7) << 4)));
        acc[t] = __builtin_amdgcn_mfma_f32_16x16x32_bf16(Ah, Bh, acc[t], 0, 0, 0);
        acc[t] = __builtin_amdgcn_mfma_f32_16x16x32_bf16(Al, Bh, acc[t], 0, 0, 0);
        acc[t] = __builtin_amdgcn_mfma_f32_16x16x32_bf16(Ah, Bl, acc[t], 0, 0, 0);
      }
    }
    __syncthreads();
  }
#pragma unroll
  for (int t = 0; t < 5; ++t) {
    int nc = n0 + wh*80 + t*16 + (lane & 15);
#pragma unroll
    for (int r = 0; r < 4; ++r) {
      int m = m0 + ((lane >> 4) << 2) + r;
      pp[((size_t)z*256 + m)*480 + nc] = acc[t][r];
    }
  }
}

// ---------------------------------------------------------------------------
// span1 reduce: sum 4 partials, route to mh1 (bias+relu) / hi / hj
// ---------------------------------------------------------------------------
__global__ __launch_bounds__(256) void k_span1r(
    const float* __restrict__ pp, const float* __restrict__ mb1,
    float* __restrict__ mh1, float* __restrict__ hi, float* __restrict__ hj) {
  const int m = blockIdx.x;
  for (int n = threadIdx.x; n < 480; n += 256) {
    float s = 0.f;
#pragma unroll
    for (int z = 0; z < 4; ++z) s += pp[((size_t)z*256 + m)*480 + n];
    if (n < 160)      mh1[m*160 + n] = (n < 150) ? fmaxf(s + mb1[n], 0.f) : 0.f;
    else if (n < 320) hi[m*160 + n - 160] = s;
    else              hj[m*160 + n - 320] = s;
  }
}

// ---------------------------------------------------------------------------
// span layers 2+3
// ---------------------------------------------------------------------------
__global__ __launch_bounds__(256) void k_span2(
    const float* __restrict__ mh1, const float* __restrict__ W2p,
    const float* __restrict__ b2, const float* __restrict__ w3,
    const float* __restrict__ b3, float* __restrict__ mo) {
  __shared__ float hs[8][160];
  const int tid = threadIdx.x;
  const int s0 = blockIdx.x * 8;
  for (int t = tid; t < 320; t += 256)
    ((float4*)&hs[0][0])[t] = ((const float4*)(mh1 + (size_t)s0*160))[t];
  __syncthreads();
  const int sp = tid >> 5, hb = tid & 31;
  float a2[5] = {0.f,0.f,0.f,0.f,0.f};
  for (int k = 0; k < 150; ++k) {
    float x = hs[sp][k];
#pragma unroll
    for (int q = 0; q < 5; ++q) a2[q] = fmaf(x, W2p[k*160 + hb + 32*q], a2[q]);
  }
  float p = 0.f;
#pragma unroll
  for (int q = 0; q < 5; ++q) {
    int h = hb + 32*q;
    if (h < 150) p += fmaxf(a2[q] + b2[h], 0.f) * w3[h];
  }
  p += __shfl_xor(p, 16, 32);
  p += __shfl_xor(p, 8, 32);
  p += __shfl_xor(p, 4, 32);
  p += __shfl_xor(p, 2, 32);
  p += __shfl_xor(p, 1, 32);
  if (hb == 0) mo[s0 + sp] = p + b3[0];
}

// ---------------------------------------------------------------------------
// Fused big einsum + pairwise MLP (k_hij4). Block = (jt in {0,1}, i in 0..255),
// tile 128j x 160h, 4 waves (wj x wh), wave 64j x 80h (4x5 frags).
// GEMM1: A = gkg[j-tile] (raw bf16, DMA, dbuf); B = Wckg RAW (DMA, dbuf);
//   the g[i,e] scale is applied IN REGISTERS inside the MFMA phase:
//   bfr' = cvtpk(unpack(Wc_frag) * g[i,e-slice]); gi prefetched 1 chunk ahead.
//   ONE barrier per chunk (m97 structure) — the stage phase is pure DMA issue.
// Then h1 -> LDS bf16, GEMM2 vs W2kg (K=160 ragged), s-reduce, out.
// LDS: A dbuf 2x16K @0; B dbuf 2x20K @32768 (= 73728).
//      GEMM2: h1' [20kg][128j][8] @0 (40K); B2 @40960 (20K); red @61440.
// ---------------------------------------------------------------------------
__global__ __launch_bounds__(256) void k_hij4(
    const float* __restrict__ g, const u16* __restrict__ gkg,
    const u16* __restrict__ Wckg, const float* __restrict__ hi,
    const float* __restrict__ hj, const float* __restrict__ pb1p,
    const u16* __restrict__ W2kg, const float* __restrict__ pb2p,
    const float* __restrict__ w3p, const float* __restrict__ pb3,
    const float* __restrict__ mv, float* __restrict__ out) {
  __shared__ __align__(16) char smem[73728];
  const int tid = threadIdx.x, lane = tid & 63, w = tid >> 6;
  const int wj = w & 1, wh = w >> 1;
  const int i = blockIdx.y, j0 = blockIdx.x * 128;

  f32x4 acc[4][5] = {};

  auto issueA = [&](int buf, int t) {
#pragma unroll
    for (int q = 0; q < 4; ++q) {
      int idx = w * 4 + q, kg = idx >> 1, seg = idx & 1;
      const u16* src = gkg + (((size_t)(t * 8 + kg)) * 256 + (j0 + seg * 64 + lane)) * 8;
      gload_lds16(src, smem + buf * 16384 + (kg * 128 + seg * 64) * 16);
    }
  };
  auto issueB = [&](int buf, int t) {
#pragma unroll
    for (int q = 0; q < 5; ++q) {
      int L = w * 5 + q;    // 0..19, 1KB each
      const u16* src = Wckg + (size_t)t * 10240 + L * 512 + lane * 8;
      gload_lds16(src, smem + 32768 + buf * 20480 + L * 1024);
    }
  };

  const float* grow = g + (size_t)i * 2304;
  const int eoff = (lane >> 4) * 8;

  float4 gcA[2], gcB[2];
  issueA(0, 0);
  issueB(0, 0);
#pragma unroll
  for (int ks = 0; ks < 2; ++ks) {
    const float* gp = grow + ks * 32 + eoff;
    gcA[ks] = *(const float4*)gp;
    gcB[ks] = *(const float4*)(gp + 4);
  }
  __syncthreads();

  for (int t = 0; t < 36; ++t) {
    const int buf = t & 1;
    float4 gnA[2], gnB[2];
    if (t < 35) {
      issueA(buf ^ 1, t + 1);
      issueB(buf ^ 1, t + 1);
#pragma unroll
      for (int ks = 0; ks < 2; ++ks) {
        const float* gp = grow + (t + 1) * 64 + ks * 32 + eoff;
        gnA[ks] = *(const float4*)gp;
        gnB[ks] = *(const float4*)(gp + 4);
      }
    }
    const char* Ab = smem + buf * 16384;
    const char* Bb = smem + 32768 + buf * 20480;
#pragma unroll
    for (int ks = 0; ks < 2; ++ks) {
      const int kgl = ks * 4 + (lane >> 4);
      bf16x8 af[4];
#pragma unroll
      for (int q = 0; q < 4; ++q)
        af[q] = *(const bf16x8*)(Ab + (kgl * 128 + wj * 64 + q * 16 + (lane & 15)) * 16);
      const float4 ga = gcA[ks], gb = gcB[ks];
#pragma unroll
      for (int u = 0; u < 5; ++u) {
        uint4 v = *(const uint4*)(Bb + kgl * 2560 + (wh * 80 + u * 16 + (lane & 15)) * 16);
        union { uint4 uu; bf16x8 bb; } r;
        r.uu.x = cvtpk(bflo(v.x) * ga.x, bfhi(v.x) * ga.y);
        r.uu.y = cvtpk(bflo(v.y) * ga.z, bfhi(v.y) * ga.w);
        r.uu.z = cvtpk(bflo(v.z) * gb.x, bfhi(v.z) * gb.y);
        r.uu.w = cvtpk(bflo(v.w) * gb.z, bfhi(v.w) * gb.w);
#pragma unroll
        for (int q = 0; q < 4; ++q)
          acc[q][u] = __builtin_amdgcn_mfma_f32_16x16x32_bf16(af[q], r.bb, acc[q][u], 0, 0, 0);
      }
    }
    gcA[0] = gnA[0]; gcA[1] = gnA[1];
    gcB[0] = gnB[0]; gcB[1] = gnB[1];
    __syncthreads();
  }

  // ---- epilogue1: h1 = relu(hij + hi + hj + pb1) -> LDS bf16 [20][128][8] --
  {
    float hib[5];
#pragma unroll
    for (int u = 0; u < 5; ++u) {
      int h = wh * 80 + u * 16 + (lane & 15);
      hib[u] = hi[i * 160 + h] + pb1p[h];
    }
#pragma unroll
    for (int q = 0; q < 4; ++q) {
      int jl = wj * 64 + q * 16 + ((lane >> 4) << 2);
#pragma unroll
      for (int r = 0; r < 4; ++r) {
        const float* hjr = hj + (size_t)(j0 + jl + r) * 160;
#pragma unroll
        for (int u = 0; u < 5; ++u) {
          int h = wh * 80 + u * 16 + (lane & 15);
          float v = fmaxf(acc[q][u][r] + hib[u] + hjr[h], 0.f);
          *(u16*)(smem + (h >> 3) * 2048 + (jl + r) * 16 + (h & 7) * 2) = f2bf(v);
        }
      }
    }
  }
  __syncthreads();

  // ---- GEMM2: h2 = h1' @ W2 (K=160), 3 chunks (8,8,4 kgrps) ----
  f32x4 acc2[4][5] = {};
  for (int c = 0; c < 3; ++c) {
    const int kgs = (c < 2) ? 8 : 4;
    const int nloads = kgs * 5 / 2;
    for (int q = w; q < nloads; q += 4) {
      const u16* src = W2kg + (size_t)c * 10240 + q * 512 + lane * 8;
      gload_lds16(src, smem + 40960 + q * 1024);
    }
    __syncthreads();
    const int nks = (c < 2) ? 2 : 1;
    for (int ks = 0; ks < nks; ++ks) {
      int kgl = ks * 4 + (lane >> 4);
      bf16x8 af2[4];
#pragma unroll
      for (int q = 0; q < 4; ++q)
        af2[q] = *(const bf16x8*)(smem + ((c * 8 + kgl) * 128 + wj * 64 + q * 16 + (lane & 15)) * 16);
#pragma unroll
      for (int u = 0; u < 5; ++u) {
        bf16x8 b2 = *(const bf16x8*)(smem + 40960 + kgl * 2560 +
                                     (wh * 80 + u * 16 + (lane & 15)) * 16);
#pragma unroll
        for (int q = 0; q < 4; ++q)
          acc2[q][u] = __builtin_amdgcn_mfma_f32_16x16x32_bf16(af2[q], b2, acc2[q][u], 0, 0, 0);
      }
    }
    __syncthreads();
  }

  // ---- epilogue2: s = relu(h2 + pb2).w3 ; out = clip((mi+mj+s)/3) ----
  {
    float w3v[5], b2v[5];
#pragma unroll
    for (int u = 0; u < 5; ++u) {
      int h2 = wh * 80 + u * 16 + (lane & 15);
      w3v[u] = w3p[h2]; b2v[u] = pb2p[h2];
    }
#pragma unroll
    for (int q = 0; q < 4; ++q) {
#pragma unroll
      for (int r = 0; r < 4; ++r) {
        float sp = 0.f;
#pragma unroll
        for (int u = 0; u < 5; ++u)
          sp += fmaxf(acc2[q][u][r] + b2v[u], 0.f) * w3v[u];
        sp += __shfl_xor(sp, 1);
        sp += __shfl_xor(sp, 2);
        sp += __shfl_xor(sp, 4);
        sp += __shfl_xor(sp, 8);
        if ((lane & 15) == 0) {
          int jl = wj * 64 + q * 16 + ((lane >> 4) << 2) + r;
          *(float*)(smem + 61440 + (jl * 2 + wh) * 4) = sp;
        }
      }
    }
  }
  __syncthreads();
  if (tid < 128) {
    float s = *(const float*)(smem + 61440 + tid * 8) +
              *(const float*)(smem + 61440 + tid * 8 + 4) + pb3[0];
    int j = j0 + tid;
    float v = (mv[i] + mv[j] + s) * (1.f / 3.f);
    v = fminf(fmaxf(v, 0.f), 1.f);
    out[i * 256 + j] = v;
  }
}

// ---------------------------------------------------------------------------
extern "C" void kernel_launch(void* const* d_in, const int* in_sizes, int n_in,
                              void* d_out, int out_size, void* d_ws, size_t ws_size,
                              hipStream_t stream) {
  (void)in_sizes; (void)n_in; (void)out_size; (void)ws_size;
  const float* e    = (const float*)d_in[0];
  const int*   sst  = (const int*)d_in[1];
  const int*   swd  = (const int*)d_in[2];
  const float* aW1  = (const float*)d_in[3];
  const float* ab1  = (const float*)d_in[4];
  const float* aW2  = (const float*)d_in[5];
  const float* ab2  = (const float*)d_in[6];
  const float* aW3  = (const float*)d_in[7];
  const float* ab3  = (const float*)d_in[8];
  const float* mW1  = (const float*)d_in[9];
  const float* mb1  = (const float*)d_in[10];
  const float* mW2  = (const float*)d_in[11];
  const float* mb2  = (const float*)d_in[12];
  const float* mW3  = (const float*)d_in[13];
  const float* mb3  = (const float*)d_in[14];
  const float* pW1  = (const float*)d_in[15];
  const float* pb1  = (const float*)d_in[16];
  const float* pW2  = (const float*)d_in[17];
  const float* pb2  = (const float*)d_in[18];
  const float* pW3  = (const float*)d_in[19];
  const float* pb3  = (const float*)d_in[20];
  float* out = (float*)d_out;

  char* ws = (char*)d_ws;
  size_t off = 0;
  auto alloc = [&](size_t bytes) -> char* {
    char* p = ws + off;
    off += (bytes + 255) & ~(size_t)255;
    return p;
  };
  float* attn  = (float*)alloc(2048ULL*4);
  float* g     = (float*)alloc(256ULL*2304*4);
  float* hi    = (float*)alloc(256ULL*160*4);
  float* hj    = (float*)alloc(256ULL*160*4);
  float* mv    = (float*)alloc(256ULL*4);
  float* h1p   = (float*)alloc(2ULL*2048*160*4);
  float* mh1   = (float*)alloc(256ULL*160*4);
  float* pp    = (float*)alloc(4ULL*256*480*4);
  u16*   aW1Th = (u16*)alloc(160ULL*768*2);
  u16*   aW1Tl = (u16*)alloc(160ULL*768*2);
  u16*   Wcath = (u16*)alloc(480ULL*2304*2);
  u16*   Wcatl = (u16*)alloc(480ULL*2304*2);
  float* aW2p  = (float*)alloc(152ULL*160*4);
  float* mW2p  = (float*)alloc(152ULL*160*4);
  u16*   gkg   = (u16*)alloc(288ULL*256*8*2);
  u16*   Wckg  = (u16*)alloc(288ULL*160*8*2);
  u16*   W2kg  = (u16*)alloc(24ULL*1280*2);
  float* pb1p  = (float*)alloc(160ULL*4);
  float* pb2p  = (float*)alloc(160ULL*4);
  float* w3p   = (float*)alloc(160ULL*4);

  k_prepT<<<dim3(36, 5), 256, 0, stream>>>(mW1, pW1, aW1,
                                           Wcath, Wcatl, aW1Th, aW1Tl, Wckg);
  k_prep0<<<128, 256, 0, stream>>>(aW2, mW2, pW2, pb1, pb2, pW3,
                                   aW2p, mW2p, W2kg, pb1p, pb2p, w3p);
  k_attn1<<<dim3(64, 2), 256, 0, stream>>>(e, aW1Th, aW1Tl, h1p);
  k_attn2<<<256, 256, 0, stream>>>(h1p, aW2p, ab1, ab2, aW3, ab3, attn);
  k_spans<<<256, 256, 0, stream>>>(e, attn, sst, swd, g, gkg);
  k_span1<<<dim3(16, 3, 4), 128, 0, stream>>>(g, Wcath, Wcatl, pp);
  k_span1r<<<256, 256, 0, stream>>>(pp, mb1, mh1, hi, hj);
  k_span2<<<32, 256, 0, stream>>>(mh1, mW2p, mb2, mW3, mb3, mv);
  k_hij4<<<dim3(2, 256), 256, 0, stream>>>(g, gkg, Wckg, hi, hj, pb1p,
                                           W2kg, pb2p, w3p, pb3, mv, out);
}

// Round 6
// 141.101 us; speedup vs baseline: 1.5451x; 1.5451x over previous
//
#include <hip/hip_runtime.h>

typedef unsigned short u16;
typedef unsigned int   u32;
typedef short bf16x8 __attribute__((ext_vector_type(8)));
typedef float f32x4  __attribute__((ext_vector_type(4)));

__device__ __forceinline__ u16 f2bf(float f) {
  union { float f; u32 u; } v; v.f = f;
  u32 u = v.u;
  u += 0x7fffu + ((u >> 16) & 1u);   // RNE
  return (u16)(u >> 16);
}

__device__ __forceinline__ void splitbf(float x, u16& hi, u16& lo) {
  hi = f2bf(x);
  union { u32 u; float f; } r; r.u = (u32)hi << 16;
  lo = f2bf(x - r.f);
}

__device__ __forceinline__ float bflo(u32 p) {
  union { u32 u; float f; } v; v.u = p << 16; return v.f;
}
__device__ __forceinline__ float bfhi(u32 p) {
  union { u32 u; float f; } v; v.u = p & 0xffff0000u; return v.f;
}
__device__ __forceinline__ u32 cvtpk(float lo, float hi) {
  u32 r;
  asm("v_cvt_pk_bf16_f32 %0, %1, %2" : "=v"(r) : "v"(lo), "v"(hi));
  return r;
}
__device__ __forceinline__ void gload_lds16(const void* src, void* dst) {
  __builtin_amdgcn_global_load_lds(
      (const __attribute__((address_space(1))) u32*)src,
      (__attribute__((address_space(3))) u32*)dst, 16, 0, 0);
}

// ---------------------------------------------------------------------------
// k_prepT: LDS-tile transpose of the big layer-1 weights.
// ---------------------------------------------------------------------------
__global__ __launch_bounds__(256) void k_prepT(
    const float* __restrict__ mW1, const float* __restrict__ pW1,
    const float* __restrict__ aW1,
    u16* __restrict__ Wcath, u16* __restrict__ Wcatl,
    u16* __restrict__ aW1Th, u16* __restrict__ aW1Tl,
    u16* __restrict__ Wckg) {
  __shared__ float ls[64][153];
  const int tid = threadIdx.x;
  const int task = blockIdx.y;
  const int e0 = blockIdx.x * 64;
  if (task == 3 && e0 >= 768) return;
  const float* src;
  if (task == 0)      src = mW1;
  else if (task == 1) src = pW1;
  else if (task == 2) src = pW1 + (size_t)2304 * 150;
  else if (task == 3) src = aW1;
  else                src = pW1 + (size_t)4608 * 150;
  for (int t = tid; t < 9600; t += 256) {
    int r = t / 150, c = t - r * 150;
    ls[r][c] = src[(size_t)(e0 + r) * 150 + c];
  }
  __syncthreads();
  if (task < 3) {
    u16* dh = Wcath + (size_t)task * 160 * 2304;
    u16* dl = Wcatl + (size_t)task * 160 * 2304;
    for (int t = tid; t < 10240; t += 256) {
      int n = t >> 6, r = t & 63;
      float v = (n < 150) ? ls[r][n] : 0.f;
      u16 h, l; splitbf(v, h, l);
      dh[(size_t)n * 2304 + e0 + r] = h;
      dl[(size_t)n * 2304 + e0 + r] = l;
    }
  } else if (task == 3) {
    for (int t = tid; t < 10240; t += 256) {
      int n = t >> 6, r = t & 63;
      float v = (n < 150) ? ls[r][n] : 0.f;
      u16 h, l; splitbf(v, h, l);
      aW1Th[(size_t)n * 768 + e0 + r] = h;
      aW1Tl[(size_t)n * 768 + e0 + r] = l;
    }
  } else {
    for (int t = tid; t < 10240; t += 256) {
      int n = t >> 6, r = t & 63;
      int e = e0 + r;
      float v = (n < 150) ? ls[r][n] : 0.f;
      Wckg[((size_t)(e >> 3) * 160 + n) * 8 + (e & 7)] = f2bf(v);
    }
  }
}

// ---------------------------------------------------------------------------
// k_prep0: small padded layouts.
// ---------------------------------------------------------------------------
__global__ __launch_bounds__(256) void k_prep0(
    const float* __restrict__ aW2, const float* __restrict__ mW2,
    const float* __restrict__ pW2, const float* __restrict__ pb1,
    const float* __restrict__ pb2, const float* __restrict__ pW3,
    float* __restrict__ aW2p, float* __restrict__ mW2p,
    u16* __restrict__ W2kg, float* __restrict__ pb1p,
    float* __restrict__ pb2p, float* __restrict__ w3p) {
  const int stride = gridDim.x * blockDim.x;
  const int t0 = blockIdx.x * blockDim.x + threadIdx.x;
  for (int t = t0; t < 152*160; t += stride) {
    int k = t / 160, h = t % 160;
    bool ok = (k < 150 && h < 150);
    aW2p[t] = ok ? aW2[k*150 + h] : 0.f;
    mW2p[t] = ok ? mW2[k*150 + h] : 0.f;
  }
  for (int t = t0; t < 24*1280; t += stride) {
    int kg = t / 1280, rem = t % 1280;
    int s = rem / 160, n = rem % 160;
    int k = kg*8 + s;
    float v = (k < 150 && n < 150) ? pW2[k*150 + n] : 0.f;
    W2kg[(size_t)kg*1280 + n*8 + s] = f2bf(v);
  }
  for (int t = t0; t < 160; t += stride) {
    pb1p[t] = (t < 150) ? pb1[t] : 0.f;
    pb2p[t] = (t < 150) ? pb2[t] : 0.f;
    w3p[t]  = (t < 150) ? pW3[t] : 0.f;
  }
}

// ---------------------------------------------------------------------------
// attn layer1 (split-bf16 MFMA GEMM, split-K x2): raw partials
// ---------------------------------------------------------------------------
__global__ __launch_bounds__(256) void k_attn1(
    const float* __restrict__ e, const u16* __restrict__ Wh,
    const u16* __restrict__ Wl, float* __restrict__ h1p) {
  __shared__ u16 lXh[32*64], lXl[32*64], lWh[160*64], lWl[160*64];
  const int tid = threadIdx.x, lane = tid & 63, w = tid >> 6;
  const int wm = w & 1, wh = w >> 1;
  const int m0 = blockIdx.x * 32;
  const int z  = blockIdx.y;
  f32x4 acc[5] = {};
  for (int e0 = z*384; e0 < (z+1)*384; e0 += 64) {
    {
      int r = tid >> 3, ec = tid & 7;
      const float* src = e + (size_t)(m0 + r)*768 + e0 + ec*8;
      float4 x0 = *(const float4*)src, x1 = *(const float4*)(src + 4);
      float xs[8] = {x0.x,x0.y,x0.z,x0.w,x1.x,x1.y,x1.z,x1.w};
      u16 hb[8], lb[8];
#pragma unroll
      for (int q = 0; q < 8; ++q) splitbf(xs[q], hb[q], lb[q]);
      int off = (r*128 + ec*16) ^ ((r & 7) << 4);
      *(uint4*)((char*)lXh + off) = make_uint4(
        (u32)hb[0]|((u32)hb[1]<<16), (u32)hb[2]|((u32)hb[3]<<16),
        (u32)hb[4]|((u32)hb[5]<<16), (u32)hb[6]|((u32)hb[7]<<16));
      *(uint4*)((char*)lXl + off) = make_uint4(
        (u32)lb[0]|((u32)lb[1]<<16), (u32)lb[2]|((u32)lb[3]<<16),
        (u32)lb[4]|((u32)lb[5]<<16), (u32)lb[6]|((u32)lb[7]<<16));
    }
#pragma unroll
    for (int t = 0; t < 5; ++t) {
      int c = tid + t*256;
      int h = c >> 3, ec = c & 7;
      int off = (h*128 + ec*16) ^ ((h & 7) << 4);
      *(uint4*)((char*)lWh + off) = *(const uint4*)(Wh + (size_t)h*768 + e0 + ec*8);
      *(uint4*)((char*)lWl + off) = *(const uint4*)(Wl + (size_t)h*768 + e0 + ec*8);
    }
    __syncthreads();
#pragma unroll
    for (int ks = 0; ks < 2; ++ks) {
      int eb = ks*64 + ((lane >> 4) << 4);
      int ar = wm*16 + (lane & 15);
      bf16x8 Ah = *(const bf16x8*)((const char*)lXh + ((ar*128 + eb) ^ ((ar & 7) << 4)));
      bf16x8 Al = *(const bf16x8*)((const char*)lXl + ((ar*128 + eb) ^ ((ar & 7) << 4)));
#pragma unroll
      for (int t = 0; t < 5; ++t) {
        int br = wh*80 + t*16 + (lane & 15);
        bf16x8 Bh = *(const bf16x8*)((const char*)lWh + ((br*128 + eb) ^ ((br & 7) << 4)));
        bf16x8 Bl = *(const bf16x8*)((const char*)lWl + ((br*128 + eb) ^ ((br & 7) << 4)));
        acc[t] = __builtin_amdgcn_mfma_f32_16x16x32_bf16(Ah, Bh, acc[t], 0, 0, 0);
        acc[t] = __builtin_amdgcn_mfma_f32_16x16x32_bf16(Al, Bh, acc[t], 0, 0, 0);
        acc[t] = __builtin_amdgcn_mfma_f32_16x16x32_bf16(Ah, Bl, acc[t], 0, 0, 0);
      }
    }
    __syncthreads();
  }
#pragma unroll
  for (int t = 0; t < 5; ++t) {
    int n = wh*80 + t*16 + (lane & 15);
#pragma unroll
    for (int r = 0; r < 4; ++r) {
      int m = m0 + wm*16 + ((lane >> 4) << 2) + r;
      h1p[((size_t)z*2048 + m)*160 + n] = acc[t][r];
    }
  }
}

// ---------------------------------------------------------------------------
// attn layers 2+3 (sums split-K partials, bias+relu, then MLP tail)
// ---------------------------------------------------------------------------
__global__ __launch_bounds__(256) void k_attn2(
    const float* __restrict__ h1p, const float* __restrict__ W2p,
    const float* __restrict__ b1, const float* __restrict__ b2,
    const float* __restrict__ w3, const float* __restrict__ b3,
    float* __restrict__ attn) {
  __shared__ float hs[8][160];
  const int tid = threadIdx.x;
  const int t0 = blockIdx.x * 8;
  for (int idx = tid; idx < 1280; idx += 256) {
    int m = idx / 160, h = idx - m * 160;
    float s = h1p[(size_t)(t0 + m)*160 + h] + h1p[(size_t)(2048 + t0 + m)*160 + h];
    hs[m][h] = (h < 150) ? fmaxf(s + b1[h], 0.f) : 0.f;
  }
  __syncthreads();
  const int sp = tid >> 5, hb = tid & 31;
  float a2[5] = {0.f,0.f,0.f,0.f,0.f};
  for (int k = 0; k < 150; ++k) {
    float x = hs[sp][k];
#pragma unroll
    for (int q = 0; q < 5; ++q) a2[q] = fmaf(x, W2p[k*160 + hb + 32*q], a2[q]);
  }
  float p = 0.f;
#pragma unroll
  for (int q = 0; q < 5; ++q) {
    int h = hb + 32*q;
    if (h < 150) p += fmaxf(a2[q] + b2[h], 0.f) * w3[h];
  }
  p += __shfl_xor(p, 16, 32);
  p += __shfl_xor(p, 8, 32);
  p += __shfl_xor(p, 4, 32);
  p += __shfl_xor(p, 2, 32);
  p += __shfl_xor(p, 1, 32);
  if (hb == 0) attn[t0 + sp] = p + b3[0];
}

// ---------------------------------------------------------------------------
// g[s] = [e[start], e[end], span_sum]; also writes gkg (k-grouped bf16)
// ---------------------------------------------------------------------------
__global__ __launch_bounds__(256) void k_spans(
    const float* __restrict__ e, const float* __restrict__ attn,
    const int* __restrict__ sstart, const int* __restrict__ swidth,
    float* __restrict__ g, u16* __restrict__ gkg) {
  const int s = blockIdx.x;
  int st = sstart[s];
  int en = st + swidth[s];
  if (en > 2047) en = 2047;
  if (en < 0) en = 0;
  const int tid = threadIdx.x;
  for (int d = tid; d < 768; d += 256) {
    float v0 = e[(size_t)st*768 + d];
    float v1 = e[(size_t)en*768 + d];
    float acc = 0.f;
    for (int t = st; t <= en; ++t) acc += e[(size_t)t*768 + d] * attn[t];
    g[s*2304 + d]        = v0;
    g[s*2304 + 768 + d]  = v1;
    g[s*2304 + 1536 + d] = acc;
    int c0 = d, c1 = 768 + d, c2 = 1536 + d;
    gkg[((size_t)(c0>>3)*256 + s)*8 + (c0&7)] = f2bf(v0);
    gkg[((size_t)(c1>>3)*256 + s)*8 + (c1&7)] = f2bf(v1);
    gkg[((size_t)(c2>>3)*256 + s)*8 + (c2&7)] = f2bf(acc);
  }
}

// ---------------------------------------------------------------------------
// span layer1 (split-bf16 MFMA GEMM, split-K x4): raw partials
// ---------------------------------------------------------------------------
__global__ __launch_bounds__(128) void k_span1(
    const float* __restrict__ g, const u16* __restrict__ Wh,
    const u16* __restrict__ Wl, float* __restrict__ pp) {
  __shared__ u16 lXh[16*64], lXl[16*64], lWh[160*64], lWl[160*64];
  const int tid = threadIdx.x, lane = tid & 63;
  const int wh = tid >> 6;
  const int m0 = blockIdx.x * 16;
  const int n0 = blockIdx.y * 160;
  const int z  = blockIdx.z;
  f32x4 acc[5] = {};
  for (int e0 = z*576; e0 < (z+1)*576; e0 += 64) {
    {
      int r = tid >> 3, ec = tid & 7;
      const float* src = g + (size_t)(m0 + r)*2304 + e0 + ec*8;
      float4 x0 = *(const float4*)src, x1 = *(const float4*)(src + 4);
      float xs[8] = {x0.x,x0.y,x0.z,x0.w,x1.x,x1.y,x1.z,x1.w};
      u16 hb[8], lb[8];
#pragma unroll
      for (int q = 0; q < 8; ++q) splitbf(xs[q], hb[q], lb[q]);
      int off = (r*128 + ec*16) ^ ((r & 7) << 4);
      *(uint4*)((char*)lXh + off) = make_uint4(
        (u32)hb[0]|((u32)hb[1]<<16), (u32)hb[2]|((u32)hb[3]<<16),
        (u32)hb[4]|((u32)hb[5]<<16), (u32)hb[6]|((u32)hb[7]<<16));
      *(uint4*)((char*)lXl + off) = make_uint4(
        (u32)lb[0]|((u32)lb[1]<<16), (u32)lb[2]|((u32)lb[3]<<16),
        (u32)lb[4]|((u32)lb[5]<<16), (u32)lb[6]|((u32)lb[7]<<16));
    }
#pragma unroll
    for (int t = 0; t < 10; ++t) {
      int c = tid + t*128;
      int h = c >> 3, ec = c & 7;
      int off = (h*128 + ec*16) ^ ((h & 7) << 4);
      *(uint4*)((char*)lWh + off) = *(const uint4*)(Wh + (size_t)(n0 + h)*2304 + e0 + ec*8);
      *(uint4*)((char*)lWl + off) = *(const uint4*)(Wl + (size_t)(n0 + h)*2304 + e0 + ec*8);
    }
    __syncthreads();
#pragma unroll
    for (int ks = 0; ks < 2; ++ks) {
      int eb = ks*64 + ((lane >> 4) << 4);
      int ar = lane & 15;
      bf16x8 Ah = *(const bf16x8*)((const char*)lXh + ((ar*128 + eb) ^ ((ar & 7) << 4)));
      bf16x8 Al = *(const bf16x8*)((const char*)lXl + ((ar*128 + eb) ^ ((ar & 7) << 4)));
#pragma unroll
      for (int t = 0; t < 5; ++t) {
        int br = wh*80 + t*16 + (lane & 15);
        bf16x8 Bh = *(const bf16x8*)((const char*)lWh + ((br*128 + eb) ^ ((br & 7) << 4)));
        bf16x8 Bl = *(const bf16x8*)((const char*)lWl + ((br*128 + eb) ^ ((br & 7) << 4)));
        acc[t] = __builtin_amdgcn_mfma_f32_16x16x32_bf16(Ah, Bh, acc[t], 0, 0, 0);
        acc[t] = __builtin_amdgcn_mfma_f32_16x16x32_bf16(Al, Bh, acc[t], 0, 0, 0);
        acc[t] = __builtin_amdgcn_mfma_f32_16x16x32_bf16(Ah, Bl, acc[t], 0, 0, 0);
      }
    }
    __syncthreads();
  }
#pragma unroll
  for (int t = 0; t < 5; ++t) {
    int nc = n0 + wh*80 + t*16 + (lane & 15);
#pragma unroll
    for (int r = 0; r < 4; ++r) {
      int m = m0 + ((lane >> 4) << 2) + r;
      pp[((size_t)z*256 + m)*480 + nc] = acc[t][r];
    }
  }
}

// ---------------------------------------------------------------------------
// span1 reduce: sum 4 partials, route to mh1 (bias+relu) / hi / hj
// ---------------------------------------------------------------------------
__global__ __launch_bounds__(256) void k_span1r(
    const float* __restrict__ pp, const float* __restrict__ mb1,
    float* __restrict__ mh1, float* __restrict__ hi, float* __restrict__ hj) {
  const int m = blockIdx.x;
  for (int n = threadIdx.x; n < 480; n += 256) {
    float s = 0.f;
#pragma unroll
    for (int z = 0; z < 4; ++z) s += pp[((size_t)z*256 + m)*480 + n];
    if (n < 160)      mh1[m*160 + n] = (n < 150) ? fmaxf(s + mb1[n], 0.f) : 0.f;
    else if (n < 320) hi[m*160 + n - 160] = s;
    else              hj[m*160 + n - 320] = s;
  }
}

// ---------------------------------------------------------------------------
// span layers 2+3
// ---------------------------------------------------------------------------
__global__ __launch_bounds__(256) void k_span2(
    const float* __restrict__ mh1, const float* __restrict__ W2p,
    const float* __restrict__ b2, const float* __restrict__ w3,
    const float* __restrict__ b3, float* __restrict__ mo) {
  __shared__ float hs[8][160];
  const int tid = threadIdx.x;
  const int s0 = blockIdx.x * 8;
  for (int t = tid; t < 320; t += 256)
    ((float4*)&hs[0][0])[t] = ((const float4*)(mh1 + (size_t)s0*160))[t];
  __syncthreads();
  const int sp = tid >> 5, hb = tid & 31;
  float a2[5] = {0.f,0.f,0.f,0.f,0.f};
  for (int k = 0; k < 150; ++k) {
    float x = hs[sp][k];
#pragma unroll
    for (int q = 0; q < 5; ++q) a2[q] = fmaf(x, W2p[k*160 + hb + 32*q], a2[q]);
  }
  float p = 0.f;
#pragma unroll
  for (int q = 0; q < 5; ++q) {
    int h = hb + 32*q;
    if (h < 150) p += fmaxf(a2[q] + b2[h], 0.f) * w3[h];
  }
  p += __shfl_xor(p, 16, 32);
  p += __shfl_xor(p, 8, 32);
  p += __shfl_xor(p, 4, 32);
  p += __shfl_xor(p, 2, 32);
  p += __shfl_xor(p, 1, 32);
  if (hb == 0) mo[s0 + sp] = p + b3[0];
}

// ---------------------------------------------------------------------------
// k_hij5: fused big einsum + pairwise MLP. ONE block per i (256 blocks,
// 512 threads = 8 waves as wj(4) x wh(2); wave tile 64j x 80h, j-span 256).
// GEMM1 per K-chunk(64): issue A-DMA(t+1) + global-load Wc/g regs(t+1);
//   MFMA(t) [setprio]; cvt+ds_write B'(t+1) to idle buffer; ONE barrier.
//   B'-scale (10240 elem) now feeds 640 MFMA/chunk -> MFMA-bound.
// Then h1 -> LDS bf16 (80KB, reuses GEMM1 LDS), GEMM2 vs W2kg (K=160),
//   s-reduce, out = clip((mv_i + mv_j + s)/3).
// LDS: A dbuf 2x32K @0; B' dbuf 2x20K @65536 (=106496 total).
//      GEMM2: h1' [20kg][256j][8] @0 (80K); B2 @81920 (20K); red @102400.
// ---------------------------------------------------------------------------
__global__ __launch_bounds__(512, 2) void k_hij5(
    const float* __restrict__ g, const u16* __restrict__ gkg,
    const u16* __restrict__ Wckg, const float* __restrict__ hi,
    const float* __restrict__ hj, const float* __restrict__ pb1p,
    const u16* __restrict__ W2kg, const float* __restrict__ pb2p,
    const float* __restrict__ w3p, const float* __restrict__ pb3,
    const float* __restrict__ mv, float* __restrict__ out) {
  __shared__ __align__(16) char smem[106496];
  const int tid = threadIdx.x, lane = tid & 63, w = tid >> 6;
  const int wj = w & 3, wh = w >> 2;
  const int i = blockIdx.x;
  const float* grow = g + (size_t)i * 2304;

  f32x4 acc[4][5] = {};
  uint4 wcR[3];
  float4 gA[3], gB[3];

  // A: [8kg][256j][8] granules; idx = (w*4+q)*64 + lane
  auto issueA = [&](int buf, int t) {
#pragma unroll
    for (int q = 0; q < 4; ++q) {
      const int base = (w * 4 + q) * 64;
      const int kg = base >> 8;
      const int jb = base & 255;
      const u16* src = gkg + (((size_t)(t * 8 + kg)) * 256 + jb + lane) * 8;
      gload_lds16(src, smem + buf * 32768 + base * 16);
    }
  };
  // B' raw inputs -> regs (granule p = kg*160+h; global = t*1280+p)
  auto loadB = [&](int t) {
#pragma unroll
    for (int z = 0; z < 2; ++z) {
      int p = tid + z * 512;
      wcR[z] = *(const uint4*)(Wckg + ((size_t)t * 1280 + p) * 8);
      const float* gp = grow + t * 64 + (p / 160) * 8;
      gA[z] = *(const float4*)gp;
      gB[z] = *(const float4*)(gp + 4);
    }
    if (tid < 256) {
      int p = tid + 1024;
      wcR[2] = *(const uint4*)(Wckg + ((size_t)t * 1280 + p) * 8);
      const float* gp = grow + t * 64 + (p / 160) * 8;
      gA[2] = *(const float4*)gp;
      gB[2] = *(const float4*)(gp + 4);
    }
  };
  auto writeB = [&](int buf) {
    char* base = smem + 65536 + buf * 20480;
#pragma unroll
    for (int z = 0; z < 2; ++z) {
      int p = tid + z * 512;
      uint4 v = wcR[z]; float4 ga = gA[z], gb = gB[z];
      uint4 r;
      r.x = cvtpk(bflo(v.x) * ga.x, bfhi(v.x) * ga.y);
      r.y = cvtpk(bflo(v.y) * ga.z, bfhi(v.y) * ga.w);
      r.z = cvtpk(bflo(v.z) * gb.x, bfhi(v.z) * gb.y);
      r.w = cvtpk(bflo(v.w) * gb.z, bfhi(v.w) * gb.w);
      *(uint4*)(base + p * 16) = r;
    }
    if (tid < 256) {
      int p = tid + 1024;
      uint4 v = wcR[2]; float4 ga = gA[2], gb = gB[2];
      uint4 r;
      r.x = cvtpk(bflo(v.x) * ga.x, bfhi(v.x) * ga.y);
      r.y = cvtpk(bflo(v.y) * ga.z, bfhi(v.y) * ga.w);
      r.z = cvtpk(bflo(v.z) * gb.x, bfhi(v.z) * gb.y);
      r.w = cvtpk(bflo(v.w) * gb.z, bfhi(v.w) * gb.w);
      *(uint4*)(base + p * 16) = r;
    }
  };

  issueA(0, 0);
  loadB(0);
  writeB(0);
  __syncthreads();

  for (int t = 0; t < 36; ++t) {
    const int buf = t & 1;
    if (t < 35) { issueA(buf ^ 1, t + 1); loadB(t + 1); }
    const char* Ab = smem + buf * 32768;
    const char* Bb = smem + 65536 + buf * 20480;
    __builtin_amdgcn_s_setprio(1);
#pragma unroll
    for (int ks = 0; ks < 2; ++ks) {
      const int kgl = ks * 4 + (lane >> 4);
      bf16x8 af[4];
#pragma unroll
      for (int q = 0; q < 4; ++q)
        af[q] = *(const bf16x8*)(Ab + (kgl * 256 + wj * 64 + q * 16 + (lane & 15)) * 16);
#pragma unroll
      for (int u = 0; u < 5; ++u) {
        bf16x8 bfr = *(const bf16x8*)(Bb + (kgl * 160 + wh * 80 + u * 16 + (lane & 15)) * 16);
#pragma unroll
        for (int q = 0; q < 4; ++q)
          acc[q][u] = __builtin_amdgcn_mfma_f32_16x16x32_bf16(af[q], bfr, acc[q][u], 0, 0, 0);
      }
    }
    __builtin_amdgcn_s_setprio(0);
    if (t < 35) writeB(buf ^ 1);
    __syncthreads();
  }

  // ---- epilogue1: h1 = relu(hij + hi + hj + pb1) -> LDS bf16 [20][256][8] --
  {
    float hib[5];
#pragma unroll
    for (int u = 0; u < 5; ++u) {
      int h = wh * 80 + u * 16 + (lane & 15);
      hib[u] = hi[i * 160 + h] + pb1p[h];
    }
#pragma unroll
    for (int q = 0; q < 4; ++q) {
      int jl = wj * 64 + q * 16 + ((lane >> 4) << 2);
#pragma unroll
      for (int r = 0; r < 4; ++r) {
        const float* hjr = hj + (size_t)(jl + r) * 160;
#pragma unroll
        for (int u = 0; u < 5; ++u) {
          int h = wh * 80 + u * 16 + (lane & 15);
          float v = fmaxf(acc[q][u][r] + hib[u] + hjr[h], 0.f);
          *(u16*)(smem + ((h >> 3) * 256 + jl + r) * 16 + (h & 7) * 2) = f2bf(v);
        }
      }
    }
  }
  __syncthreads();

  // ---- GEMM2: h2 = h1' @ W2 (K=160), 3 chunks (8,8,4 kgrps) ----
  f32x4 acc2[4][5] = {};
  for (int c = 0; c < 3; ++c) {
    const int G64 = (c < 2) ? 20 : 10;    // 64-granule groups this chunk
    for (int g0 = w; g0 < G64; g0 += 8) {
      const u16* src = W2kg + ((size_t)c * 1280 + g0 * 64 + lane) * 8;
      gload_lds16(src, smem + 81920 + g0 * 1024);
    }
    __syncthreads();
    const int nks = (c < 2) ? 2 : 1;
    for (int ks = 0; ks < nks; ++ks) {
      const int kl = ks * 4 + (lane >> 4);
      bf16x8 af2[4];
#pragma unroll
      for (int q = 0; q < 4; ++q)
        af2[q] = *(const bf16x8*)(smem + ((c * 8 + kl) * 256 + wj * 64 + q * 16 + (lane & 15)) * 16);
#pragma unroll
      for (int u = 0; u < 5; ++u) {
        bf16x8 b2 = *(const bf16x8*)(smem + 81920 + (kl * 160 + wh * 80 + u * 16 + (lane & 15)) * 16);
#pragma unroll
        for (int q = 0; q < 4; ++q)
          acc2[q][u] = __builtin_amdgcn_mfma_f32_16x16x32_bf16(af2[q], b2, acc2[q][u], 0, 0, 0);
      }
    }
    __syncthreads();
  }

  // ---- epilogue2: s = relu(h2 + pb2).w3 ; out = clip((mi+mj+s)/3) ----
  {
    float w3v[5], b2v[5];
#pragma unroll
    for (int u = 0; u < 5; ++u) {
      int h2 = wh * 80 + u * 16 + (lane & 15);
      w3v[u] = w3p[h2]; b2v[u] = pb2p[h2];
    }
#pragma unroll
    for (int q = 0; q < 4; ++q) {
#pragma unroll
      for (int r = 0; r < 4; ++r) {
        float sp = 0.f;
#pragma unroll
        for (int u = 0; u < 5; ++u)
          sp += fmaxf(acc2[q][u][r] + b2v[u], 0.f) * w3v[u];
        sp += __shfl_xor(sp, 1);
        sp += __shfl_xor(sp, 2);
        sp += __shfl_xor(sp, 4);
        sp += __shfl_xor(sp, 8);
        if ((lane & 15) == 0) {
          int jl = wj * 64 + q * 16 + ((lane >> 4) << 2) + r;
          *(float*)(smem + 102400 + (jl * 2 + wh) * 4) = sp;
        }
      }
    }
  }
  __syncthreads();
  if (tid < 256) {
    float s = *(const float*)(smem + 102400 + tid * 8) +
              *(const float*)(smem + 102400 + tid * 8 + 4) + pb3[0];
    float v = (mv[i] + mv[tid] + s) * (1.f / 3.f);
    out[i * 256 + tid] = fminf(fmaxf(v, 0.f), 1.f);
  }
}

// ---------------------------------------------------------------------------
extern "C" void kernel_launch(void* const* d_in, const int* in_sizes, int n_in,
                              void* d_out, int out_size, void* d_ws, size_t ws_size,
                              hipStream_t stream) {
  (void)in_sizes; (void)n_in; (void)out_size; (void)ws_size;
  const float* e    = (const float*)d_in[0];
  const int*   sst  = (const int*)d_in[1];
  const int*   swd  = (const int*)d_in[2];
  const float* aW1  = (const float*)d_in[3];
  const float* ab1  = (const float*)d_in[4];
  const float* aW2  = (const float*)d_in[5];
  const float* ab2  = (const float*)d_in[6];
  const float* aW3  = (const float*)d_in[7];
  const float* ab3  = (const float*)d_in[8];
  const float* mW1  = (const float*)d_in[9];
  const float* mb1  = (const float*)d_in[10];
  const float* mW2  = (const float*)d_in[11];
  const float* mb2  = (const float*)d_in[12];
  const float* mW3  = (const float*)d_in[13];
  const float* mb3  = (const float*)d_in[14];
  const float* pW1  = (const float*)d_in[15];
  const float* pb1  = (const float*)d_in[16];
  const float* pW2  = (const float*)d_in[17];
  const float* pb2  = (const float*)d_in[18];
  const float* pW3  = (const float*)d_in[19];
  const float* pb3  = (const float*)d_in[20];
  float* out = (float*)d_out;

  char* ws = (char*)d_ws;
  size_t off = 0;
  auto alloc = [&](size_t bytes) -> char* {
    char* p = ws + off;
    off += (bytes + 255) & ~(size_t)255;
    return p;
  };
  float* attn  = (float*)alloc(2048ULL*4);
  float* g     = (float*)alloc(256ULL*2304*4);
  float* hi    = (float*)alloc(256ULL*160*4);
  float* hj    = (float*)alloc(256ULL*160*4);
  float* mv    = (float*)alloc(256ULL*4);
  float* h1p   = (float*)alloc(2ULL*2048*160*4);
  float* mh1   = (float*)alloc(256ULL*160*4);
  float* pp    = (float*)alloc(4ULL*256*480*4);
  u16*   aW1Th = (u16*)alloc(160ULL*768*2);
  u16*   aW1Tl = (u16*)alloc(160ULL*768*2);
  u16*   Wcath = (u16*)alloc(480ULL*2304*2);
  u16*   Wcatl = (u16*)alloc(480ULL*2304*2);
  float* aW2p  = (float*)alloc(152ULL*160*4);
  float* mW2p  = (float*)alloc(152ULL*160*4);
  u16*   gkg   = (u16*)alloc(288ULL*256*8*2);
  u16*   Wckg  = (u16*)alloc(288ULL*160*8*2);
  u16*   W2kg  = (u16*)alloc(24ULL*1280*2);
  float* pb1p  = (float*)alloc(160ULL*4);
  float* pb2p  = (float*)alloc(160ULL*4);
  float* w3p   = (float*)alloc(160ULL*4);

  k_prepT<<<dim3(36, 5), 256, 0, stream>>>(mW1, pW1, aW1,
                                           Wcath, Wcatl, aW1Th, aW1Tl, Wckg);
  k_prep0<<<128, 256, 0, stream>>>(aW2, mW2, pW2, pb1, pb2, pW3,
                                   aW2p, mW2p, W2kg, pb1p, pb2p, w3p);
  k_attn1<<<dim3(64, 2), 256, 0, stream>>>(e, aW1Th, aW1Tl, h1p);
  k_attn2<<<256, 256, 0, stream>>>(h1p, aW2p, ab1, ab2, aW3, ab3, attn);
  k_spans<<<256, 256, 0, stream>>>(e, attn, sst, swd, g, gkg);
  k_span1<<<dim3(16, 3, 4), 128, 0, stream>>>(g, Wcath, Wcatl, pp);
  k_span1r<<<256, 256, 0, stream>>>(pp, mb1, mh1, hi, hj);
  k_span2<<<32, 256, 0, stream>>>(mh1, mW2p, mb2, mW3, mb3, mv);
  k_hij5<<<256, 512, 0, stream>>>(g, gkg, Wckg, hi, hj, pb1p,
                                  W2kg, pb2p, w3p, pb3, mv, out);
}

// Round 7
// 138.338 us; speedup vs baseline: 1.5760x; 1.0200x over previous
//
#include <hip/hip_runtime.h>

typedef unsigned short u16;
typedef unsigned int   u32;
typedef short bf16x8 __attribute__((ext_vector_type(8)));
typedef float f32x4  __attribute__((ext_vector_type(4)));

__device__ __forceinline__ u16 f2bf(float f) {
  union { float f; u32 u; } v; v.f = f;
  u32 u = v.u;
  u += 0x7fffu + ((u >> 16) & 1u);   // RNE
  return (u16)(u >> 16);
}

__device__ __forceinline__ void splitbf(float x, u16& hi, u16& lo) {
  hi = f2bf(x);
  union { u32 u; float f; } r; r.u = (u32)hi << 16;
  lo = f2bf(x - r.f);
}

__device__ __forceinline__ float bflo(u32 p) {
  union { u32 u; float f; } v; v.u = p << 16; return v.f;
}
__device__ __forceinline__ float bfhi(u32 p) {
  union { u32 u; float f; } v; v.u = p & 0xffff0000u; return v.f;
}
__device__ __forceinline__ u32 cvtpk(float lo, float hi) {
  u32 r;
  asm("v_cvt_pk_bf16_f32 %0, %1, %2" : "=v"(r) : "v"(lo), "v"(hi));
  return r;
}
__device__ __forceinline__ void gload_lds16(const void* src, void* dst) {
  __builtin_amdgcn_global_load_lds(
      (const __attribute__((address_space(1))) u32*)src,
      (__attribute__((address_space(3))) u32*)dst, 16, 0, 0);
}

// ---------------------------------------------------------------------------
// k_prepT: LDS-tile transpose of the big layer-1 weights + small layouts.
//  task 0..2: {mW1, pW1a, pW1b} [2304][150] -> Wcath/l [480][2304] (split bf16)
//  task 3   : aW1 [768][150]    -> aW1Th/l [160][768]
//  task 4   : pW1c [2304][150]  -> Wckg [288 grp][160 h][8 s] bf16
//  task 5   : small padded layouts (was k_prep0)
// ---------------------------------------------------------------------------
__global__ __launch_bounds__(256) void k_prepT(
    const float* __restrict__ mW1, const float* __restrict__ pW1,
    const float* __restrict__ aW1, const float* __restrict__ aW2,
    const float* __restrict__ mW2, const float* __restrict__ pW2,
    const float* __restrict__ pb1, const float* __restrict__ pb2,
    const float* __restrict__ pW3,
    u16* __restrict__ Wcath, u16* __restrict__ Wcatl,
    u16* __restrict__ aW1Th, u16* __restrict__ aW1Tl,
    u16* __restrict__ Wckg,
    float* __restrict__ aW2p, float* __restrict__ mW2p,
    u16* __restrict__ W2kg, float* __restrict__ pb1p,
    float* __restrict__ pb2p, float* __restrict__ w3p) {
  __shared__ float ls[64][153];
  const int tid = threadIdx.x;
  const int task = blockIdx.y;
  const int e0 = blockIdx.x * 64;
  if (task == 5) {
    const int stride = 36 * 256;
    const int t0 = blockIdx.x * 256 + tid;
    for (int t = t0; t < 152*160; t += stride) {
      int k = t / 160, h = t % 160;
      bool ok = (k < 150 && h < 150);
      aW2p[t] = ok ? aW2[k*150 + h] : 0.f;
      mW2p[t] = ok ? mW2[k*150 + h] : 0.f;
    }
    for (int t = t0; t < 24*1280; t += stride) {
      int kg = t / 1280, rem = t % 1280;
      int s = rem / 160, n = rem % 160;
      int k = kg*8 + s;
      float v = (k < 150 && n < 150) ? pW2[k*150 + n] : 0.f;
      W2kg[(size_t)kg*1280 + n*8 + s] = f2bf(v);
    }
    for (int t = t0; t < 160; t += stride) {
      pb1p[t] = (t < 150) ? pb1[t] : 0.f;
      pb2p[t] = (t < 150) ? pb2[t] : 0.f;
      w3p[t]  = (t < 150) ? pW3[t] : 0.f;
    }
    return;
  }
  if (task == 3 && e0 >= 768) return;
  const float* src;
  if (task == 0)      src = mW1;
  else if (task == 1) src = pW1;
  else if (task == 2) src = pW1 + (size_t)2304 * 150;
  else if (task == 3) src = aW1;
  else                src = pW1 + (size_t)4608 * 150;
  for (int t = tid; t < 9600; t += 256) {
    int r = t / 150, c = t - r * 150;
    ls[r][c] = src[(size_t)(e0 + r) * 150 + c];
  }
  __syncthreads();
  if (task < 3) {
    u16* dh = Wcath + (size_t)task * 160 * 2304;
    u16* dl = Wcatl + (size_t)task * 160 * 2304;
    for (int t = tid; t < 10240; t += 256) {
      int n = t >> 6, r = t & 63;
      float v = (n < 150) ? ls[r][n] : 0.f;
      u16 h, l; splitbf(v, h, l);
      dh[(size_t)n * 2304 + e0 + r] = h;
      dl[(size_t)n * 2304 + e0 + r] = l;
    }
  } else if (task == 3) {
    for (int t = tid; t < 10240; t += 256) {
      int n = t >> 6, r = t & 63;
      float v = (n < 150) ? ls[r][n] : 0.f;
      u16 h, l; splitbf(v, h, l);
      aW1Th[(size_t)n * 768 + e0 + r] = h;
      aW1Tl[(size_t)n * 768 + e0 + r] = l;
    }
  } else {
    for (int t = tid; t < 10240; t += 256) {
      int n = t >> 6, r = t & 63;
      int e = e0 + r;
      float v = (n < 150) ? ls[r][n] : 0.f;
      Wckg[((size_t)(e >> 3) * 160 + n) * 8 + (e & 7)] = f2bf(v);
    }
  }
}

// ---------------------------------------------------------------------------
// attn layer1 (split-bf16 MFMA GEMM, split-K x2): raw partials
// ---------------------------------------------------------------------------
__global__ __launch_bounds__(256) void k_attn1(
    const float* __restrict__ e, const u16* __restrict__ Wh,
    const u16* __restrict__ Wl, float* __restrict__ h1p) {
  __shared__ u16 lXh[32*64], lXl[32*64], lWh[160*64], lWl[160*64];
  const int tid = threadIdx.x, lane = tid & 63, w = tid >> 6;
  const int wm = w & 1, wh = w >> 1;
  const int m0 = blockIdx.x * 32;
  const int z  = blockIdx.y;
  f32x4 acc[5] = {};
  for (int e0 = z*384; e0 < (z+1)*384; e0 += 64) {
    {
      int r = tid >> 3, ec = tid & 7;
      const float* src = e + (size_t)(m0 + r)*768 + e0 + ec*8;
      float4 x0 = *(const float4*)src, x1 = *(const float4*)(src + 4);
      float xs[8] = {x0.x,x0.y,x0.z,x0.w,x1.x,x1.y,x1.z,x1.w};
      u16 hb[8], lb[8];
#pragma unroll
      for (int q = 0; q < 8; ++q) splitbf(xs[q], hb[q], lb[q]);
      int off = (r*128 + ec*16) ^ ((r & 7) << 4);
      *(uint4*)((char*)lXh + off) = make_uint4(
        (u32)hb[0]|((u32)hb[1]<<16), (u32)hb[2]|((u32)hb[3]<<16),
        (u32)hb[4]|((u32)hb[5]<<16), (u32)hb[6]|((u32)hb[7]<<16));
      *(uint4*)((char*)lXl + off) = make_uint4(
        (u32)lb[0]|((u32)lb[1]<<16), (u32)lb[2]|((u32)lb[3]<<16),
        (u32)lb[4]|((u32)lb[5]<<16), (u32)lb[6]|((u32)lb[7]<<16));
    }
#pragma unroll
    for (int t = 0; t < 5; ++t) {
      int c = tid + t*256;
      int h = c >> 3, ec = c & 7;
      int off = (h*128 + ec*16) ^ ((h & 7) << 4);
      *(uint4*)((char*)lWh + off) = *(const uint4*)(Wh + (size_t)h*768 + e0 + ec*8);
      *(uint4*)((char*)lWl + off) = *(const uint4*)(Wl + (size_t)h*768 + e0 + ec*8);
    }
    __syncthreads();
#pragma unroll
    for (int ks = 0; ks < 2; ++ks) {
      int eb = ks*64 + ((lane >> 4) << 4);
      int ar = wm*16 + (lane & 15);
      bf16x8 Ah = *(const bf16x8*)((const char*)lXh + ((ar*128 + eb) ^ ((ar & 7) << 4)));
      bf16x8 Al = *(const bf16x8*)((const char*)lXl + ((ar*128 + eb) ^ ((ar & 7) << 4)));
#pragma unroll
      for (int t = 0; t < 5; ++t) {
        int br = wh*80 + t*16 + (lane & 15);
        bf16x8 Bh = *(const bf16x8*)((const char*)lWh + ((br*128 + eb) ^ ((br & 7) << 4)));
        bf16x8 Bl = *(const bf16x8*)((const char*)lWl + ((br*128 + eb) ^ ((br & 7) << 4)));
        acc[t] = __builtin_amdgcn_mfma_f32_16x16x32_bf16(Ah, Bh, acc[t], 0, 0, 0);
        acc[t] = __builtin_amdgcn_mfma_f32_16x16x32_bf16(Al, Bh, acc[t], 0, 0, 0);
        acc[t] = __builtin_amdgcn_mfma_f32_16x16x32_bf16(Ah, Bl, acc[t], 0, 0, 0);
      }
    }
    __syncthreads();
  }
#pragma unroll
  for (int t = 0; t < 5; ++t) {
    int n = wh*80 + t*16 + (lane & 15);
#pragma unroll
    for (int r = 0; r < 4; ++r) {
      int m = m0 + wm*16 + ((lane >> 4) << 2) + r;
      h1p[((size_t)z*2048 + m)*160 + n] = acc[t][r];
    }
  }
}

// ---------------------------------------------------------------------------
// attn layers 2+3 (sums split-K partials, bias+relu, then MLP tail)
// ---------------------------------------------------------------------------
__global__ __launch_bounds__(256) void k_attn2(
    const float* __restrict__ h1p, const float* __restrict__ W2p,
    const float* __restrict__ b1, const float* __restrict__ b2,
    const float* __restrict__ w3, const float* __restrict__ b3,
    float* __restrict__ attn) {
  __shared__ float hs[8][160];
  const int tid = threadIdx.x;
  const int t0 = blockIdx.x * 8;
  for (int idx = tid; idx < 1280; idx += 256) {
    int m = idx / 160, h = idx - m * 160;
    float s = h1p[(size_t)(t0 + m)*160 + h] + h1p[(size_t)(2048 + t0 + m)*160 + h];
    hs[m][h] = (h < 150) ? fmaxf(s + b1[h], 0.f) : 0.f;
  }
  __syncthreads();
  const int sp = tid >> 5, hb = tid & 31;
  float a2[5] = {0.f,0.f,0.f,0.f,0.f};
  for (int k = 0; k < 150; ++k) {
    float x = hs[sp][k];
#pragma unroll
    for (int q = 0; q < 5; ++q) a2[q] = fmaf(x, W2p[k*160 + hb + 32*q], a2[q]);
  }
  float p = 0.f;
#pragma unroll
  for (int q = 0; q < 5; ++q) {
    int h = hb + 32*q;
    if (h < 150) p += fmaxf(a2[q] + b2[h], 0.f) * w3[h];
  }
  p += __shfl_xor(p, 16, 32);
  p += __shfl_xor(p, 8, 32);
  p += __shfl_xor(p, 4, 32);
  p += __shfl_xor(p, 2, 32);
  p += __shfl_xor(p, 1, 32);
  if (hb == 0) attn[t0 + sp] = p + b3[0];
}

// ---------------------------------------------------------------------------
// g[s] = [e[start], e[end], span_sum]; also writes gkg (k-grouped bf16)
// ---------------------------------------------------------------------------
__global__ __launch_bounds__(256) void k_spans(
    const float* __restrict__ e, const float* __restrict__ attn,
    const int* __restrict__ sstart, const int* __restrict__ swidth,
    float* __restrict__ g, u16* __restrict__ gkg) {
  const int s = blockIdx.x;
  int st = sstart[s];
  int en = st + swidth[s];
  if (en > 2047) en = 2047;
  if (en < 0) en = 0;
  const int tid = threadIdx.x;
  for (int d = tid; d < 768; d += 256) {
    float v0 = e[(size_t)st*768 + d];
    float v1 = e[(size_t)en*768 + d];
    float acc = 0.f;
    for (int t = st; t <= en; ++t) acc += e[(size_t)t*768 + d] * attn[t];
    g[s*2304 + d]        = v0;
    g[s*2304 + 768 + d]  = v1;
    g[s*2304 + 1536 + d] = acc;
    int c0 = d, c1 = 768 + d, c2 = 1536 + d;
    gkg[((size_t)(c0>>3)*256 + s)*8 + (c0&7)] = f2bf(v0);
    gkg[((size_t)(c1>>3)*256 + s)*8 + (c1&7)] = f2bf(v1);
    gkg[((size_t)(c2>>3)*256 + s)*8 + (c2&7)] = f2bf(acc);
  }
}

// ---------------------------------------------------------------------------
// span layer1 (split-bf16 MFMA GEMM, split-K x4): raw partials
// ---------------------------------------------------------------------------
__global__ __launch_bounds__(128) void k_span1(
    const float* __restrict__ g, const u16* __restrict__ Wh,
    const u16* __restrict__ Wl, float* __restrict__ pp) {
  __shared__ u16 lXh[16*64], lXl[16*64], lWh[160*64], lWl[160*64];
  const int tid = threadIdx.x, lane = tid & 63;
  const int wh = tid >> 6;
  const int m0 = blockIdx.x * 16;
  const int n0 = blockIdx.y * 160;
  const int z  = blockIdx.z;
  f32x4 acc[5] = {};
  for (int e0 = z*576; e0 < (z+1)*576; e0 += 64) {
    {
      int r = tid >> 3, ec = tid & 7;
      const float* src = g + (size_t)(m0 + r)*2304 + e0 + ec*8;
      float4 x0 = *(const float4*)src, x1 = *(const float4*)(src + 4);
      float xs[8] = {x0.x,x0.y,x0.z,x0.w,x1.x,x1.y,x1.z,x1.w};
      u16 hb[8], lb[8];
#pragma unroll
      for (int q = 0; q < 8; ++q) splitbf(xs[q], hb[q], lb[q]);
      int off = (r*128 + ec*16) ^ ((r & 7) << 4);
      *(uint4*)((char*)lXh + off) = make_uint4(
        (u32)hb[0]|((u32)hb[1]<<16), (u32)hb[2]|((u32)hb[3]<<16),
        (u32)hb[4]|((u32)hb[5]<<16), (u32)hb[6]|((u32)hb[7]<<16));
      *(uint4*)((char*)lXl + off) = make_uint4(
        (u32)lb[0]|((u32)lb[1]<<16), (u32)lb[2]|((u32)lb[3]<<16),
        (u32)lb[4]|((u32)lb[5]<<16), (u32)lb[6]|((u32)lb[7]<<16));
    }
#pragma unroll
    for (int t = 0; t < 10; ++t) {
      int c = tid + t*128;
      int h = c >> 3, ec = c & 7;
      int off = (h*128 + ec*16) ^ ((h & 7) << 4);
      *(uint4*)((char*)lWh + off) = *(const uint4*)(Wh + (size_t)(n0 + h)*2304 + e0 + ec*8);
      *(uint4*)((char*)lWl + off) = *(const uint4*)(Wl + (size_t)(n0 + h)*2304 + e0 + ec*8);
    }
    __syncthreads();
#pragma unroll
    for (int ks = 0; ks < 2; ++ks) {
      int eb = ks*64 + ((lane >> 4) << 4);
      int ar = lane & 15;
      bf16x8 Ah = *(const bf16x8*)((const char*)lXh + ((ar*128 + eb) ^ ((ar & 7) << 4)));
      bf16x8 Al = *(const bf16x8*)((const char*)lXl + ((ar*128 + eb) ^ ((ar & 7) << 4)));
#pragma unroll
      for (int t = 0; t < 5; ++t) {
        int br = wh*80 + t*16 + (lane & 15);
        bf16x8 Bh = *(const bf16x8*)((const char*)lWh + ((br*128 + eb) ^ ((br & 7) << 4)));
        bf16x8 Bl = *(const bf16x8*)((const char*)lWl + ((br*128 + eb) ^ ((br & 7) << 4)));
        acc[t] = __builtin_amdgcn_mfma_f32_16x16x32_bf16(Ah, Bh, acc[t], 0, 0, 0);
        acc[t] = __builtin_amdgcn_mfma_f32_16x16x32_bf16(Al, Bh, acc[t], 0, 0, 0);
        acc[t] = __builtin_amdgcn_mfma_f32_16x16x32_bf16(Ah, Bl, acc[t], 0, 0, 0);
      }
    }
    __syncthreads();
  }
#pragma unroll
  for (int t = 0; t < 5; ++t) {
    int nc = n0 + wh*80 + t*16 + (lane & 15);
#pragma unroll
    for (int r = 0; r < 4; ++r) {
      int m = m0 + ((lane >> 4) << 2) + r;
      pp[((size_t)z*256 + m)*480 + nc] = acc[t][r];
    }
  }
}

// ---------------------------------------------------------------------------
// span reduce + layers 2+3 (merged): sum 4 split-K partials -> mh1(LDS)/hi/hj,
// then mo[s] = relu(mh1 @ mW2 + b2) . w3 + b3. 8 spans/block, 32 blocks.
// ---------------------------------------------------------------------------
__global__ __launch_bounds__(256) void k_span2r(
    const float* __restrict__ pp, const float* __restrict__ mb1,
    const float* __restrict__ W2p, const float* __restrict__ b2,
    const float* __restrict__ w3, const float* __restrict__ b3,
    float* __restrict__ hi, float* __restrict__ hj, float* __restrict__ mo) {
  __shared__ float hs[8][160];
  const int tid = threadIdx.x;
  const int s0 = blockIdx.x * 8;
  for (int idx = tid; idx < 3840; idx += 256) {
    int mr = idx / 480, n = idx - mr * 480;
    int m = s0 + mr;
    float s = 0.f;
#pragma unroll
    for (int z = 0; z < 4; ++z) s += pp[((size_t)z*256 + m)*480 + n];
    if (n < 160)      hs[mr][n] = (n < 150) ? fmaxf(s + mb1[n], 0.f) : 0.f;
    else if (n < 320) hi[m*160 + n - 160] = s;
    else              hj[m*160 + n - 320] = s;
  }
  __syncthreads();
  const int sp = tid >> 5, hb = tid & 31;
  float a2[5] = {0.f,0.f,0.f,0.f,0.f};
  for (int k = 0; k < 150; ++k) {
    float x = hs[sp][k];
#pragma unroll
    for (int q = 0; q < 5; ++q) a2[q] = fmaf(x, W2p[k*160 + hb + 32*q], a2[q]);
  }
  float p = 0.f;
#pragma unroll
  for (int q = 0; q < 5; ++q) {
    int h = hb + 32*q;
    if (h < 150) p += fmaxf(a2[q] + b2[h], 0.f) * w3[h];
  }
  p += __shfl_xor(p, 16, 32);
  p += __shfl_xor(p, 8, 32);
  p += __shfl_xor(p, 4, 32);
  p += __shfl_xor(p, 2, 32);
  p += __shfl_xor(p, 1, 32);
  if (hb == 0) mo[s0 + sp] = p + b3[0];
}

// ---------------------------------------------------------------------------
// k_hij6: fused big einsum + pairwise MLP. ONE block per i (256 blocks,
// 512 threads = 8 waves as wj(4) x wh(2); wave tile 64j x 80h, j-span 256).
// A-fragments load GLOBAL->VGPR directly from gkg (no LDS for A): each wave's
//   bf16x8 fragment = four contiguous 256B segments of the k-grouped layout.
//   A(t+1) loads issued AFTER the last MFMA read of the A regs (WAR-safe);
//   latency hides under writeB + barrier.
// B' (= g[i,e] .* Wc) double-buffered in LDS, reg-staged: loadB(t+1) early,
//   MFMA(t) [setprio], writeB(t+1), ONE barrier. LDS/chunk = 100KB (B' only).
// Then h1 -> LDS bf16, GEMM2 vs W2kg (K=160), s-reduce, out.
// LDS: B' dbuf 2x20480 @0; GEMM2: h1' [20kg][256j][8] @0 (80K);
//      B2 @81920 (20K); red @102400. Total 104448.
// ---------------------------------------------------------------------------
__global__ __launch_bounds__(512, 2) void k_hij6(
    const float* __restrict__ g, const u16* __restrict__ gkg,
    const u16* __restrict__ Wckg, const float* __restrict__ hi,
    const float* __restrict__ hj, const float* __restrict__ pb1p,
    const u16* __restrict__ W2kg, const float* __restrict__ pb2p,
    const float* __restrict__ w3p, const float* __restrict__ pb3,
    const float* __restrict__ mv, float* __restrict__ out) {
  __shared__ __align__(16) char smem[104448];
  const int tid = threadIdx.x, lane = tid & 63, w = tid >> 6;
  const int wj = w & 3, wh = w >> 2;
  const int i = blockIdx.x;
  const float* grow = g + (size_t)i * 2304;

  f32x4 acc[4][5] = {};
  bf16x8 afC[8];
  uint4 wcR[3];
  float4 gA[3], gB[3];

  // per-thread hoisted bases
  const u16* pA = gkg + (((lane >> 4) * 256) + wj * 64 + (lane & 15)) * 8;
  const int ep0 = (tid / 160) * 8;
  const int ep1 = ((tid + 512) / 160) * 8;
  const int ep2 = ((tid + 1024) / 160) * 8;
  const int bB = (((lane >> 4) * 160) + wh * 80 + (lane & 15)) * 16;

  auto loadA = [&](int t) {
    const u16* p = pA + (size_t)t * 16384;
#pragma unroll
    for (int ks = 0; ks < 2; ++ks)
#pragma unroll
      for (int q = 0; q < 4; ++q)
        afC[ks * 4 + q] = *(const bf16x8*)(p + ks * 8192 + q * 128);
  };
  auto loadB = [&](int t) {
    const u16* wp = Wckg + (size_t)t * 10240;
    const float* gp = grow + t * 64;
    wcR[0] = *(const uint4*)(wp + (size_t)tid * 8);
    gA[0] = *(const float4*)(gp + ep0); gB[0] = *(const float4*)(gp + ep0 + 4);
    wcR[1] = *(const uint4*)(wp + (size_t)(tid + 512) * 8);
    gA[1] = *(const float4*)(gp + ep1); gB[1] = *(const float4*)(gp + ep1 + 4);
    if (tid < 256) {
      wcR[2] = *(const uint4*)(wp + (size_t)(tid + 1024) * 8);
      gA[2] = *(const float4*)(gp + ep2); gB[2] = *(const float4*)(gp + ep2 + 4);
    }
  };
  auto writeB = [&](int buf) {
    char* base = smem + buf * 20480;
#pragma unroll
    for (int z = 0; z < 2; ++z) {
      uint4 v = wcR[z]; float4 ga = gA[z], gb = gB[z];
      uint4 r;
      r.x = cvtpk(bflo(v.x) * ga.x, bfhi(v.x) * ga.y);
      r.y = cvtpk(bflo(v.y) * ga.z, bfhi(v.y) * ga.w);
      r.z = cvtpk(bflo(v.z) * gb.x, bfhi(v.z) * gb.y);
      r.w = cvtpk(bflo(v.w) * gb.z, bfhi(v.w) * gb.w);
      *(uint4*)(base + (tid + z * 512) * 16) = r;
    }
    if (tid < 256) {
      uint4 v = wcR[2]; float4 ga = gA[2], gb = gB[2];
      uint4 r;
      r.x = cvtpk(bflo(v.x) * ga.x, bfhi(v.x) * ga.y);
      r.y = cvtpk(bflo(v.y) * ga.z, bfhi(v.y) * ga.w);
      r.z = cvtpk(bflo(v.z) * gb.x, bfhi(v.z) * gb.y);
      r.w = cvtpk(bflo(v.w) * gb.z, bfhi(v.w) * gb.w);
      *(uint4*)(base + (tid + 1024) * 16) = r;
    }
  };

  loadA(0);
  loadB(0);
  writeB(0);
  __syncthreads();

  for (int t = 0; t < 36; ++t) {
    const int buf = t & 1;
    if (t < 35) loadB(t + 1);
    const char* Bb = smem + buf * 20480;
    __builtin_amdgcn_s_setprio(1);
#pragma unroll
    for (int ks = 0; ks < 2; ++ks) {
#pragma unroll
      for (int u = 0; u < 5; ++u) {
        bf16x8 bfr = *(const bf16x8*)(Bb + bB + ks * 10240 + u * 256);
#pragma unroll
        for (int q = 0; q < 4; ++q)
          acc[q][u] = __builtin_amdgcn_mfma_f32_16x16x32_bf16(
              afC[ks * 4 + q], bfr, acc[q][u], 0, 0, 0);
      }
    }
    __builtin_amdgcn_s_setprio(0);
    if (t < 35) { loadA(t + 1); writeB(buf ^ 1); }
    __syncthreads();
  }

  // ---- epilogue1: h1 = relu(hij + hi + hj + pb1) -> LDS bf16 [20][256][8] --
  {
    float hib[5];
#pragma unroll
    for (int u = 0; u < 5; ++u) {
      int h = wh * 80 + u * 16 + (lane & 15);
      hib[u] = hi[i * 160 + h] + pb1p[h];
    }
#pragma unroll
    for (int q = 0; q < 4; ++q) {
      int jl = wj * 64 + q * 16 + ((lane >> 4) << 2);
#pragma unroll
      for (int r = 0; r < 4; ++r) {
        const float* hjr = hj + (size_t)(jl + r) * 160;
#pragma unroll
        for (int u = 0; u < 5; ++u) {
          int h = wh * 80 + u * 16 + (lane & 15);
          float v = fmaxf(acc[q][u][r] + hib[u] + hjr[h], 0.f);
          *(u16*)(smem + ((h >> 3) * 256 + jl + r) * 16 + (h & 7) * 2) = f2bf(v);
        }
      }
    }
  }
  __syncthreads();

  // ---- GEMM2: h2 = h1' @ W2 (K=160), 3 chunks (8,8,4 kgrps) ----
  f32x4 acc2[4][5] = {};
  for (int c = 0; c < 3; ++c) {
    const int G64 = (c < 2) ? 20 : 10;
    for (int g0 = w; g0 < G64; g0 += 8) {
      const u16* src = W2kg + ((size_t)c * 1280 + g0 * 64 + lane) * 8;
      gload_lds16(src, smem + 81920 + g0 * 1024);
    }
    __syncthreads();
    const int nks = (c < 2) ? 2 : 1;
    for (int ks = 0; ks < nks; ++ks) {
      const int kl = ks * 4 + (lane >> 4);
      bf16x8 af2[4];
#pragma unroll
      for (int q = 0; q < 4; ++q)
        af2[q] = *(const bf16x8*)(smem + ((c * 8 + kl) * 256 + wj * 64 + q * 16 + (lane & 15)) * 16);
#pragma unroll
      for (int u = 0; u < 5; ++u) {
        bf16x8 b2 = *(const bf16x8*)(smem + 81920 + (kl * 160 + wh * 80 + u * 16 + (lane & 15)) * 16);
#pragma unroll
        for (int q = 0; q < 4; ++q)
          acc2[q][u] = __builtin_amdgcn_mfma_f32_16x16x32_bf16(af2[q], b2, acc2[q][u], 0, 0, 0);
      }
    }
    __syncthreads();
  }

  // ---- epilogue2: s = relu(h2 + pb2).w3 ; out = clip((mi+mj+s)/3) ----
  {
    float w3v[5], b2v[5];
#pragma unroll
    for (int u = 0; u < 5; ++u) {
      int h2 = wh * 80 + u * 16 + (lane & 15);
      w3v[u] = w3p[h2]; b2v[u] = pb2p[h2];
    }
#pragma unroll
    for (int q = 0; q < 4; ++q) {
#pragma unroll
      for (int r = 0; r < 4; ++r) {
        float sp = 0.f;
#pragma unroll
        for (int u = 0; u < 5; ++u)
          sp += fmaxf(acc2[q][u][r] + b2v[u], 0.f) * w3v[u];
        sp += __shfl_xor(sp, 1);
        sp += __shfl_xor(sp, 2);
        sp += __shfl_xor(sp, 4);
        sp += __shfl_xor(sp, 8);
        if ((lane & 15) == 0) {
          int jl = wj * 64 + q * 16 + ((lane >> 4) << 2) + r;
          *(float*)(smem + 102400 + (jl * 2 + wh) * 4) = sp;
        }
      }
    }
  }
  __syncthreads();
  if (tid < 256) {
    float s = *(const float*)(smem + 102400 + tid * 8) +
              *(const float*)(smem + 102400 + tid * 8 + 4) + pb3[0];
    float v = (mv[i] + mv[tid] + s) * (1.f / 3.f);
    out[i * 256 + tid] = fminf(fmaxf(v, 0.f), 1.f);
  }
}

// ---------------------------------------------------------------------------
extern "C" void kernel_launch(void* const* d_in, const int* in_sizes, int n_in,
                              void* d_out, int out_size, void* d_ws, size_t ws_size,
                              hipStream_t stream) {
  (void)in_sizes; (void)n_in; (void)out_size; (void)ws_size;
  const float* e    = (const float*)d_in[0];
  const int*   sst  = (const int*)d_in[1];
  const int*   swd  = (const int*)d_in[2];
  const float* aW1  = (const float*)d_in[3];
  const float* ab1  = (const float*)d_in[4];
  const float* aW2  = (const float*)d_in[5];
  const float* ab2  = (const float*)d_in[6];
  const float* aW3  = (const float*)d_in[7];
  const float* ab3  = (const float*)d_in[8];
  const float* mW1  = (const float*)d_in[9];
  const float* mb1  = (const float*)d_in[10];
  const float* mW2  = (const float*)d_in[11];
  const float* mb2  = (const float*)d_in[12];
  const float* mW3  = (const float*)d_in[13];
  const float* mb3  = (const float*)d_in[14];
  const float* pW1  = (const float*)d_in[15];
  const float* pb1  = (const float*)d_in[16];
  const float* pW2  = (const float*)d_in[17];
  const float* pb2  = (const float*)d_in[18];
  const float* pW3  = (const float*)d_in[19];
  const float* pb3  = (const float*)d_in[20];
  float* out = (float*)d_out;

  char* ws = (char*)d_ws;
  size_t off = 0;
  auto alloc = [&](size_t bytes) -> char* {
    char* p = ws + off;
    off += (bytes + 255) & ~(size_t)255;
    return p;
  };
  float* attn  = (float*)alloc(2048ULL*4);
  float* g     = (float*)alloc(256ULL*2304*4);
  float* hi    = (float*)alloc(256ULL*160*4);
  float* hj    = (float*)alloc(256ULL*160*4);
  float* mv    = (float*)alloc(256ULL*4);
  float* h1p   = (float*)alloc(2ULL*2048*160*4);
  float* pp    = (float*)alloc(4ULL*256*480*4);
  u16*   aW1Th = (u16*)alloc(160ULL*768*2);
  u16*   aW1Tl = (u16*)alloc(160ULL*768*2);
  u16*   Wcath = (u16*)alloc(480ULL*2304*2);
  u16*   Wcatl = (u16*)alloc(480ULL*2304*2);
  float* aW2p  = (float*)alloc(152ULL*160*4);
  float* mW2p  = (float*)alloc(152ULL*160*4);
  u16*   gkg   = (u16*)alloc(288ULL*256*8*2);
  u16*   Wckg  = (u16*)alloc(288ULL*160*8*2);
  u16*   W2kg  = (u16*)alloc(24ULL*1280*2);
  float* pb1p  = (float*)alloc(160ULL*4);
  float* pb2p  = (float*)alloc(160ULL*4);
  float* w3p   = (float*)alloc(160ULL*4);

  k_prepT<<<dim3(36, 6), 256, 0, stream>>>(mW1, pW1, aW1, aW2, mW2, pW2,
                                           pb1, pb2, pW3,
                                           Wcath, Wcatl, aW1Th, aW1Tl, Wckg,
                                           aW2p, mW2p, W2kg, pb1p, pb2p, w3p);
  k_attn1<<<dim3(64, 2), 256, 0, stream>>>(e, aW1Th, aW1Tl, h1p);
  k_attn2<<<256, 256, 0, stream>>>(h1p, aW2p, ab1, ab2, aW3, ab3, attn);
  k_spans<<<256, 256, 0, stream>>>(e, attn, sst, swd, g, gkg);
  k_span1<<<dim3(16, 3, 4), 128, 0, stream>>>(g, Wcath, Wcatl, pp);
  k_span2r<<<32, 256, 0, stream>>>(pp, mb1, mW2p, mb2, mW3, mb3, hi, hj, mv);
  k_hij6<<<256, 512, 0, stream>>>(g, gkg, Wckg, hi, hj, pb1p,
                                  W2kg, pb2p, w3p, pb3, mv, out);
}

// Round 8
// 134.156 us; speedup vs baseline: 1.6251x; 1.0312x over previous
//
#include <hip/hip_runtime.h>

typedef unsigned short u16;
typedef unsigned int   u32;
typedef short bf16x8 __attribute__((ext_vector_type(8)));
typedef float f32x4  __attribute__((ext_vector_type(4)));

__device__ __forceinline__ u16 f2bf(float f) {
  union { float f; u32 u; } v; v.f = f;
  u32 u = v.u;
  u += 0x7fffu + ((u >> 16) & 1u);   // RNE
  return (u16)(u >> 16);
}

__device__ __forceinline__ void splitbf(float x, u16& hi, u16& lo) {
  hi = f2bf(x);
  union { u32 u; float f; } r; r.u = (u32)hi << 16;
  lo = f2bf(x - r.f);
}

__device__ __forceinline__ float bflo(u32 p) {
  union { u32 u; float f; } v; v.u = p << 16; return v.f;
}
__device__ __forceinline__ float bfhi(u32 p) {
  union { u32 u; float f; } v; v.u = p & 0xffff0000u; return v.f;
}
__device__ __forceinline__ u32 cvtpk(float lo, float hi) {
  u32 r;
  asm("v_cvt_pk_bf16_f32 %0, %1, %2" : "=v"(r) : "v"(lo), "v"(hi));
  return r;
}
__device__ __forceinline__ void gload_lds16(const void* src, void* dst) {
  __builtin_amdgcn_global_load_lds(
      (const __attribute__((address_space(1))) u32*)src,
      (__attribute__((address_space(3))) u32*)dst, 16, 0, 0);
}

// ---------------------------------------------------------------------------
// k_prepT: LDS-tile transpose of the big layer-1 weights + small layouts.
// ---------------------------------------------------------------------------
__global__ __launch_bounds__(256) void k_prepT(
    const float* __restrict__ mW1, const float* __restrict__ pW1,
    const float* __restrict__ aW1, const float* __restrict__ aW2,
    const float* __restrict__ mW2, const float* __restrict__ pW2,
    const float* __restrict__ pb1, const float* __restrict__ pb2,
    const float* __restrict__ pW3,
    u16* __restrict__ Wcath, u16* __restrict__ Wcatl,
    u16* __restrict__ aW1Th, u16* __restrict__ aW1Tl,
    u16* __restrict__ Wckg,
    float* __restrict__ aW2p, float* __restrict__ mW2p,
    u16* __restrict__ W2kg, float* __restrict__ pb1p,
    float* __restrict__ pb2p, float* __restrict__ w3p) {
  __shared__ float ls[64][153];
  const int tid = threadIdx.x;
  const int task = blockIdx.y;
  const int e0 = blockIdx.x * 64;
  if (task == 5) {
    const int stride = 36 * 256;
    const int t0 = blockIdx.x * 256 + tid;
    for (int t = t0; t < 152*160; t += stride) {
      int k = t / 160, h = t % 160;
      bool ok = (k < 150 && h < 150);
      aW2p[t] = ok ? aW2[k*150 + h] : 0.f;
      mW2p[t] = ok ? mW2[k*150 + h] : 0.f;
    }
    for (int t = t0; t < 24*1280; t += stride) {
      int kg = t / 1280, rem = t % 1280;
      int s = rem / 160, n = rem % 160;
      int k = kg*8 + s;
      float v = (k < 150 && n < 150) ? pW2[k*150 + n] : 0.f;
      W2kg[(size_t)kg*1280 + n*8 + s] = f2bf(v);
    }
    for (int t = t0; t < 160; t += stride) {
      pb1p[t] = (t < 150) ? pb1[t] : 0.f;
      pb2p[t] = (t < 150) ? pb2[t] : 0.f;
      w3p[t]  = (t < 150) ? pW3[t] : 0.f;
    }
    return;
  }
  if (task == 3 && e0 >= 768) return;
  const float* src;
  if (task == 0)      src = mW1;
  else if (task == 1) src = pW1;
  else if (task == 2) src = pW1 + (size_t)2304 * 150;
  else if (task == 3) src = aW1;
  else                src = pW1 + (size_t)4608 * 150;
  for (int t = tid; t < 9600; t += 256) {
    int r = t / 150, c = t - r * 150;
    ls[r][c] = src[(size_t)(e0 + r) * 150 + c];
  }
  __syncthreads();
  if (task < 3) {
    u16* dh = Wcath + (size_t)task * 160 * 2304;
    u16* dl = Wcatl + (size_t)task * 160 * 2304;
    for (int t = tid; t < 10240; t += 256) {
      int n = t >> 6, r = t & 63;
      float v = (n < 150) ? ls[r][n] : 0.f;
      u16 h, l; splitbf(v, h, l);
      dh[(size_t)n * 2304 + e0 + r] = h;
      dl[(size_t)n * 2304 + e0 + r] = l;
    }
  } else if (task == 3) {
    for (int t = tid; t < 10240; t += 256) {
      int n = t >> 6, r = t & 63;
      float v = (n < 150) ? ls[r][n] : 0.f;
      u16 h, l; splitbf(v, h, l);
      aW1Th[(size_t)n * 768 + e0 + r] = h;
      aW1Tl[(size_t)n * 768 + e0 + r] = l;
    }
  } else {
    for (int t = tid; t < 10240; t += 256) {
      int n = t >> 6, r = t & 63;
      int e = e0 + r;
      float v = (n < 150) ? ls[r][n] : 0.f;
      Wckg[((size_t)(e >> 3) * 160 + n) * 8 + (e & 7)] = f2bf(v);
    }
  }
}

// ---------------------------------------------------------------------------
// attn layer1 (split-bf16 MFMA GEMM, split-K x4): raw partials
// ---------------------------------------------------------------------------
__global__ __launch_bounds__(256) void k_attn1(
    const float* __restrict__ e, const u16* __restrict__ Wh,
    const u16* __restrict__ Wl, float* __restrict__ h1p) {
  __shared__ u16 lXh[32*64], lXl[32*64], lWh[160*64], lWl[160*64];
  const int tid = threadIdx.x, lane = tid & 63, w = tid >> 6;
  const int wm = w & 1, wh = w >> 1;
  const int m0 = blockIdx.x * 32;
  const int z  = blockIdx.y;
  f32x4 acc[5] = {};
  for (int e0 = z*192; e0 < (z+1)*192; e0 += 64) {
    {
      int r = tid >> 3, ec = tid & 7;
      const float* src = e + (size_t)(m0 + r)*768 + e0 + ec*8;
      float4 x0 = *(const float4*)src, x1 = *(const float4*)(src + 4);
      float xs[8] = {x0.x,x0.y,x0.z,x0.w,x1.x,x1.y,x1.z,x1.w};
      u16 hb[8], lb[8];
#pragma unroll
      for (int q = 0; q < 8; ++q) splitbf(xs[q], hb[q], lb[q]);
      int off = (r*128 + ec*16) ^ ((r & 7) << 4);
      *(uint4*)((char*)lXh + off) = make_uint4(
        (u32)hb[0]|((u32)hb[1]<<16), (u32)hb[2]|((u32)hb[3]<<16),
        (u32)hb[4]|((u32)hb[5]<<16), (u32)hb[6]|((u32)hb[7]<<16));
      *(uint4*)((char*)lXl + off) = make_uint4(
        (u32)lb[0]|((u32)lb[1]<<16), (u32)lb[2]|((u32)lb[3]<<16),
        (u32)lb[4]|((u32)lb[5]<<16), (u32)lb[6]|((u32)lb[7]<<16));
    }
#pragma unroll
    for (int t = 0; t < 5; ++t) {
      int c = tid + t*256;
      int h = c >> 3, ec = c & 7;
      int off = (h*128 + ec*16) ^ ((h & 7) << 4);
      *(uint4*)((char*)lWh + off) = *(const uint4*)(Wh + (size_t)h*768 + e0 + ec*8);
      *(uint4*)((char*)lWl + off) = *(const uint4*)(Wl + (size_t)h*768 + e0 + ec*8);
    }
    __syncthreads();
#pragma unroll
    for (int ks = 0; ks < 2; ++ks) {
      int eb = ks*64 + ((lane >> 4) << 4);
      int ar = wm*16 + (lane & 15);
      bf16x8 Ah = *(const bf16x8*)((const char*)lXh + ((ar*128 + eb) ^ ((ar & 7) << 4)));
      bf16x8 Al = *(const bf16x8*)((const char*)lXl + ((ar*128 + eb) ^ ((ar & 7) << 4)));
#pragma unroll
      for (int t = 0; t < 5; ++t) {
        int br = wh*80 + t*16 + (lane & 15);
        bf16x8 Bh = *(const bf16x8*)((const char*)lWh + ((br*128 + eb) ^ ((br & 7) << 4)));
        bf16x8 Bl = *(const bf16x8*)((const char*)lWl + ((br*128 + eb) ^ ((br & 7) << 4)));
        acc[t] = __builtin_amdgcn_mfma_f32_16x16x32_bf16(Ah, Bh, acc[t], 0, 0, 0);
        acc[t] = __builtin_amdgcn_mfma_f32_16x16x32_bf16(Al, Bh, acc[t], 0, 0, 0);
        acc[t] = __builtin_amdgcn_mfma_f32_16x16x32_bf16(Ah, Bl, acc[t], 0, 0, 0);
      }
    }
    __syncthreads();
  }
#pragma unroll
  for (int t = 0; t < 5; ++t) {
    int n = wh*80 + t*16 + (lane & 15);
#pragma unroll
    for (int r = 0; r < 4; ++r) {
      int m = m0 + wm*16 + ((lane >> 4) << 2) + r;
      h1p[((size_t)z*2048 + m)*160 + n] = acc[t][r];
    }
  }
}

// ---------------------------------------------------------------------------
// attn layers 2+3 (sums 4 split-K partials, bias+relu, then MLP tail)
// ---------------------------------------------------------------------------
__global__ __launch_bounds__(256) void k_attn2(
    const float* __restrict__ h1p, const float* __restrict__ W2p,
    const float* __restrict__ b1, const float* __restrict__ b2,
    const float* __restrict__ w3, const float* __restrict__ b3,
    float* __restrict__ attn) {
  __shared__ float hs[8][160];
  const int tid = threadIdx.x;
  const int t0 = blockIdx.x * 8;
  for (int idx = tid; idx < 1280; idx += 256) {
    int m = idx / 160, h = idx - m * 160;
    float s = 0.f;
#pragma unroll
    for (int z = 0; z < 4; ++z)
      s += h1p[((size_t)z*2048 + t0 + m)*160 + h];
    hs[m][h] = (h < 150) ? fmaxf(s + b1[h], 0.f) : 0.f;
  }
  __syncthreads();
  const int sp = tid >> 5, hb = tid & 31;
  float a2[5] = {0.f,0.f,0.f,0.f,0.f};
  for (int k = 0; k < 150; ++k) {
    float x = hs[sp][k];
#pragma unroll
    for (int q = 0; q < 5; ++q) a2[q] = fmaf(x, W2p[k*160 + hb + 32*q], a2[q]);
  }
  float p = 0.f;
#pragma unroll
  for (int q = 0; q < 5; ++q) {
    int h = hb + 32*q;
    if (h < 150) p += fmaxf(a2[q] + b2[h], 0.f) * w3[h];
  }
  p += __shfl_xor(p, 16, 32);
  p += __shfl_xor(p, 8, 32);
  p += __shfl_xor(p, 4, 32);
  p += __shfl_xor(p, 2, 32);
  p += __shfl_xor(p, 1, 32);
  if (hb == 0) attn[t0 + sp] = p + b3[0];
}

// ---------------------------------------------------------------------------
// g[s] = [e[start], e[end], span_sum]; also writes gkg (k-grouped bf16)
// ---------------------------------------------------------------------------
__global__ __launch_bounds__(256) void k_spans(
    const float* __restrict__ e, const float* __restrict__ attn,
    const int* __restrict__ sstart, const int* __restrict__ swidth,
    float* __restrict__ g, u16* __restrict__ gkg) {
  const int s = blockIdx.x;
  int st = sstart[s];
  int en = st + swidth[s];
  if (en > 2047) en = 2047;
  if (en < 0) en = 0;
  const int tid = threadIdx.x;
  for (int d = tid; d < 768; d += 256) {
    float v0 = e[(size_t)st*768 + d];
    float v1 = e[(size_t)en*768 + d];
    float acc = 0.f;
    for (int t = st; t <= en; ++t) acc += e[(size_t)t*768 + d] * attn[t];
    g[s*2304 + d]        = v0;
    g[s*2304 + 768 + d]  = v1;
    g[s*2304 + 1536 + d] = acc;
    int c0 = d, c1 = 768 + d, c2 = 1536 + d;
    gkg[((size_t)(c0>>3)*256 + s)*8 + (c0&7)] = f2bf(v0);
    gkg[((size_t)(c1>>3)*256 + s)*8 + (c1&7)] = f2bf(v1);
    gkg[((size_t)(c2>>3)*256 + s)*8 + (c2&7)] = f2bf(acc);
  }
}

// ---------------------------------------------------------------------------
// span layer1 (split-bf16 MFMA GEMM, split-K x6): raw partials
// ---------------------------------------------------------------------------
__global__ __launch_bounds__(128) void k_span1(
    const float* __restrict__ g, const u16* __restrict__ Wh,
    const u16* __restrict__ Wl, float* __restrict__ pp) {
  __shared__ u16 lXh[16*64], lXl[16*64], lWh[160*64], lWl[160*64];
  const int tid = threadIdx.x, lane = tid & 63;
  const int wh = tid >> 6;
  const int m0 = blockIdx.x * 16;
  const int n0 = blockIdx.y * 160;
  const int z  = blockIdx.z;
  f32x4 acc[5] = {};
  for (int e0 = z*384; e0 < (z+1)*384; e0 += 64) {
    {
      int r = tid >> 3, ec = tid & 7;
      const float* src = g + (size_t)(m0 + r)*2304 + e0 + ec*8;
      float4 x0 = *(const float4*)src, x1 = *(const float4*)(src + 4);
      float xs[8] = {x0.x,x0.y,x0.z,x0.w,x1.x,x1.y,x1.z,x1.w};
      u16 hb[8], lb[8];
#pragma unroll
      for (int q = 0; q < 8; ++q) splitbf(xs[q], hb[q], lb[q]);
      int off = (r*128 + ec*16) ^ ((r & 7) << 4);
      *(uint4*)((char*)lXh + off) = make_uint4(
        (u32)hb[0]|((u32)hb[1]<<16), (u32)hb[2]|((u32)hb[3]<<16),
        (u32)hb[4]|((u32)hb[5]<<16), (u32)hb[6]|((u32)hb[7]<<16));
      *(uint4*)((char*)lXl + off) = make_uint4(
        (u32)lb[0]|((u32)lb[1]<<16), (u32)lb[2]|((u32)lb[3]<<16),
        (u32)lb[4]|((u32)lb[5]<<16), (u32)lb[6]|((u32)lb[7]<<16));
    }
#pragma unroll
    for (int t = 0; t < 10; ++t) {
      int c = tid + t*128;
      int h = c >> 3, ec = c & 7;
      int off = (h*128 + ec*16) ^ ((h & 7) << 4);
      *(uint4*)((char*)lWh + off) = *(const uint4*)(Wh + (size_t)(n0 + h)*2304 + e0 + ec*8);
      *(uint4*)((char*)lWl + off) = *(const uint4*)(Wl + (size_t)(n0 + h)*2304 + e0 + ec*8);
    }
    __syncthreads();
#pragma unroll
    for (int ks = 0; ks < 2; ++ks) {
      int eb = ks*64 + ((lane >> 4) << 4);
      int ar = lane & 15;
      bf16x8 Ah = *(const bf16x8*)((const char*)lXh + ((ar*128 + eb) ^ ((ar & 7) << 4)));
      bf16x8 Al = *(const bf16x8*)((const char*)lXl + ((ar*128 + eb) ^ ((ar & 7) << 4)));
#pragma unroll
      for (int t = 0; t < 5; ++t) {
        int br = wh*80 + t*16 + (lane & 15);
        bf16x8 Bh = *(const bf16x8*)((const char*)lWh + ((br*128 + eb) ^ ((br & 7) << 4)));
        bf16x8 Bl = *(const bf16x8*)((const char*)lWl + ((br*128 + eb) ^ ((br & 7) << 4)));
        acc[t] = __builtin_amdgcn_mfma_f32_16x16x32_bf16(Ah, Bh, acc[t], 0, 0, 0);
        acc[t] = __builtin_amdgcn_mfma_f32_16x16x32_bf16(Al, Bh, acc[t], 0, 0, 0);
        acc[t] = __builtin_amdgcn_mfma_f32_16x16x32_bf16(Ah, Bl, acc[t], 0, 0, 0);
      }
    }
    __syncthreads();
  }
#pragma unroll
  for (int t = 0; t < 5; ++t) {
    int nc = n0 + wh*80 + t*16 + (lane & 15);
#pragma unroll
    for (int r = 0; r < 4; ++r) {
      int m = m0 + ((lane >> 4) << 2) + r;
      pp[((size_t)z*256 + m)*480 + nc] = acc[t][r];
    }
  }
}

// ---------------------------------------------------------------------------
// span reduce + layers 2+3 (merged): sum 6 split-K partials -> mh1(LDS)/hi/hj,
// then mo[s] = relu(mh1 @ mW2 + b2) . w3 + b3. 8 spans/block, 32 blocks.
// ---------------------------------------------------------------------------
__global__ __launch_bounds__(256) void k_span2r(
    const float* __restrict__ pp, const float* __restrict__ mb1,
    const float* __restrict__ W2p, const float* __restrict__ b2,
    const float* __restrict__ w3, const float* __restrict__ b3,
    float* __restrict__ hi, float* __restrict__ hj, float* __restrict__ mo) {
  __shared__ float hs[8][160];
  const int tid = threadIdx.x;
  const int s0 = blockIdx.x * 8;
  for (int idx = tid; idx < 3840; idx += 256) {
    int mr = idx / 480, n = idx - mr * 480;
    int m = s0 + mr;
    float s = 0.f;
#pragma unroll
    for (int z = 0; z < 6; ++z) s += pp[((size_t)z*256 + m)*480 + n];
    if (n < 160)      hs[mr][n] = (n < 150) ? fmaxf(s + mb1[n], 0.f) : 0.f;
    else if (n < 320) hi[m*160 + n - 160] = s;
    else              hj[m*160 + n - 320] = s;
  }
  __syncthreads();
  const int sp = tid >> 5, hb = tid & 31;
  float a2[5] = {0.f,0.f,0.f,0.f,0.f};
  for (int k = 0; k < 150; ++k) {
    float x = hs[sp][k];
#pragma unroll
    for (int q = 0; q < 5; ++q) a2[q] = fmaf(x, W2p[k*160 + hb + 32*q], a2[q]);
  }
  float p = 0.f;
#pragma unroll
  for (int q = 0; q < 5; ++q) {
    int h = hb + 32*q;
    if (h < 150) p += fmaxf(a2[q] + b2[h], 0.f) * w3[h];
  }
  p += __shfl_xor(p, 16, 32);
  p += __shfl_xor(p, 8, 32);
  p += __shfl_xor(p, 4, 32);
  p += __shfl_xor(p, 2, 32);
  p += __shfl_xor(p, 1, 32);
  if (hb == 0) mo[s0 + sp] = p + b3[0];
}

// ---------------------------------------------------------------------------
// k_hij7: fused big einsum + pairwise MLP. ONE block per i (256 blocks,
// 512 threads = 8 waves as wj(4) x wh(2); wave tile 64j x 80h, j-span 256).
// GEMM1 loop uses RAW s_barrier + lgkmcnt(0)-only wait (counted vmcnt left to
// the compiler's per-register waits) so loadA/loadB global latency spans the
// barrier instead of being drained by __syncthreads' vmcnt(0).
// Hazards: chunk t reads buf=t&1, writes buf^1; end-of-chunk barrier separates
// all RAW/WAR pairs; ds_writes made visible by lgkmcnt(0)+barrier; global
// loads are register-private. sched_barrier(0) pins ordering (rule #18).
// LDS: B' dbuf 2x20480 @0; then h1' [20kg][256j][8] @0 (80K);
//      B2 @81920 (20K); red @102400. Total 104448.
// ---------------------------------------------------------------------------
__global__ __launch_bounds__(512, 2) void k_hij7(
    const float* __restrict__ g, const u16* __restrict__ gkg,
    const u16* __restrict__ Wckg, const float* __restrict__ hi,
    const float* __restrict__ hj, const float* __restrict__ pb1p,
    const u16* __restrict__ W2kg, const float* __restrict__ pb2p,
    const float* __restrict__ w3p, const float* __restrict__ pb3,
    const float* __restrict__ mv, float* __restrict__ out) {
  __shared__ __align__(16) char smem[104448];
  const int tid = threadIdx.x, lane = tid & 63, w = tid >> 6;
  const int wj = w & 3, wh = w >> 2;
  const int i = blockIdx.x;
  const float* grow = g + (size_t)i * 2304;

  f32x4 acc[4][5] = {};
  bf16x8 afC[8];
  uint4 wcR[3];
  float4 gA[3], gB[3];

  const u16* pA = gkg + (((lane >> 4) * 256) + wj * 64 + (lane & 15)) * 8;
  const int ep0 = (tid / 160) * 8;
  const int ep1 = ((tid + 512) / 160) * 8;
  const int ep2 = ((tid + 1024) / 160) * 8;
  const int bB = (((lane >> 4) * 160) + wh * 80 + (lane & 15)) * 16;

  auto loadA = [&](int t) {
    const u16* p = pA + (size_t)t * 16384;
#pragma unroll
    for (int ks = 0; ks < 2; ++ks)
#pragma unroll
      for (int q = 0; q < 4; ++q)
        afC[ks * 4 + q] = *(const bf16x8*)(p + ks * 8192 + q * 128);
  };
  auto loadB = [&](int t) {
    const u16* wp = Wckg + (size_t)t * 10240;
    const float* gp = grow + t * 64;
    wcR[0] = *(const uint4*)(wp + (size_t)tid * 8);
    gA[0] = *(const float4*)(gp + ep0); gB[0] = *(const float4*)(gp + ep0 + 4);
    wcR[1] = *(const uint4*)(wp + (size_t)(tid + 512) * 8);
    gA[1] = *(const float4*)(gp + ep1); gB[1] = *(const float4*)(gp + ep1 + 4);
    if (tid < 256) {
      wcR[2] = *(const uint4*)(wp + (size_t)(tid + 1024) * 8);
      gA[2] = *(const float4*)(gp + ep2); gB[2] = *(const float4*)(gp + ep2 + 4);
    }
  };
  auto writeB = [&](int buf) {
    char* base = smem + buf * 20480;
#pragma unroll
    for (int z = 0; z < 2; ++z) {
      uint4 v = wcR[z]; float4 ga = gA[z], gb = gB[z];
      uint4 r;
      r.x = cvtpk(bflo(v.x) * ga.x, bfhi(v.x) * ga.y);
      r.y = cvtpk(bflo(v.y) * ga.z, bfhi(v.y) * ga.w);
      r.z = cvtpk(bflo(v.z) * gb.x, bfhi(v.z) * gb.y);
      r.w = cvtpk(bflo(v.w) * gb.z, bfhi(v.w) * gb.w);
      *(uint4*)(base + (tid + z * 512) * 16) = r;
    }
    if (tid < 256) {
      uint4 v = wcR[2]; float4 ga = gA[2], gb = gB[2];
      uint4 r;
      r.x = cvtpk(bflo(v.x) * ga.x, bfhi(v.x) * ga.y);
      r.y = cvtpk(bflo(v.y) * ga.z, bfhi(v.y) * ga.w);
      r.z = cvtpk(bflo(v.z) * gb.x, bfhi(v.z) * gb.y);
      r.w = cvtpk(bflo(v.w) * gb.z, bfhi(v.w) * gb.w);
      *(uint4*)(base + (tid + 1024) * 16) = r;
    }
  };

  // prologue: loadB first (older) so writeB's wait leaves loadA outstanding
  loadB(0);
  loadA(0);
  writeB(0);
  asm volatile("s_waitcnt lgkmcnt(0)" ::: "memory");
  __builtin_amdgcn_s_barrier();
  __builtin_amdgcn_sched_barrier(0);

  for (int t = 0; t < 36; ++t) {
    const int buf = t & 1;
    if (t < 35) loadB(t + 1);
    const char* Bb = smem + buf * 20480;
    __builtin_amdgcn_s_setprio(1);
#pragma unroll
    for (int ks = 0; ks < 2; ++ks) {
#pragma unroll
      for (int u = 0; u < 5; ++u) {
        bf16x8 bfr = *(const bf16x8*)(Bb + bB + ks * 10240 + u * 256);
#pragma unroll
        for (int q = 0; q < 4; ++q)
          acc[q][u] = __builtin_amdgcn_mfma_f32_16x16x32_bf16(
              afC[ks * 4 + q], bfr, acc[q][u], 0, 0, 0);
      }
    }
    __builtin_amdgcn_s_setprio(0);
    if (t < 35) { loadA(t + 1); writeB(buf ^ 1); }
    // visibility: this wave's ds_writes (and completed ds_reads) only —
    // global loads legally stay in flight across the barrier.
    asm volatile("s_waitcnt lgkmcnt(0)" ::: "memory");
    __builtin_amdgcn_s_barrier();
    __builtin_amdgcn_sched_barrier(0);
  }

  // ---- epilogue1: h1 = relu(hij + hi + hj + pb1) -> LDS bf16 [20][256][8] --
  {
    float hib[5];
#pragma unroll
    for (int u = 0; u < 5; ++u) {
      int h = wh * 80 + u * 16 + (lane & 15);
      hib[u] = hi[i * 160 + h] + pb1p[h];
    }
#pragma unroll
    for (int q = 0; q < 4; ++q) {
      int jl = wj * 64 + q * 16 + ((lane >> 4) << 2);
#pragma unroll
      for (int r = 0; r < 4; ++r) {
        const float* hjr = hj + (size_t)(jl + r) * 160;
#pragma unroll
        for (int u = 0; u < 5; ++u) {
          int h = wh * 80 + u * 16 + (lane & 15);
          float v = fmaxf(acc[q][u][r] + hib[u] + hjr[h], 0.f);
          *(u16*)(smem + ((h >> 3) * 256 + jl + r) * 16 + (h & 7) * 2) = f2bf(v);
        }
      }
    }
  }
  __syncthreads();

  // ---- GEMM2: h2 = h1' @ W2 (K=160), 3 chunks (8,8,4 kgrps) ----
  f32x4 acc2[4][5] = {};
  for (int c = 0; c < 3; ++c) {
    const int G64 = (c < 2) ? 20 : 10;
    for (int g0 = w; g0 < G64; g0 += 8) {
      const u16* src = W2kg + ((size_t)c * 1280 + g0 * 64 + lane) * 8;
      gload_lds16(src, smem + 81920 + g0 * 1024);
    }
    __syncthreads();
    const int nks = (c < 2) ? 2 : 1;
    for (int ks = 0; ks < nks; ++ks) {
      const int kl = ks * 4 + (lane >> 4);
      bf16x8 af2[4];
#pragma unroll
      for (int q = 0; q < 4; ++q)
        af2[q] = *(const bf16x8*)(smem + ((c * 8 + kl) * 256 + wj * 64 + q * 16 + (lane & 15)) * 16);
#pragma unroll
      for (int u = 0; u < 5; ++u) {
        bf16x8 b2 = *(const bf16x8*)(smem + 81920 + (kl * 160 + wh * 80 + u * 16 + (lane & 15)) * 16);
#pragma unroll
        for (int q = 0; q < 4; ++q)
          acc2[q][u] = __builtin_amdgcn_mfma_f32_16x16x32_bf16(af2[q], b2, acc2[q][u], 0, 0, 0);
      }
    }
    __syncthreads();
  }

  // ---- epilogue2: s = relu(h2 + pb2).w3 ; out = clip((mi+mj+s)/3) ----
  {
    float w3v[5], b2v[5];
#pragma unroll
    for (int u = 0; u < 5; ++u) {
      int h2 = wh * 80 + u * 16 + (lane & 15);
      w3v[u] = w3p[h2]; b2v[u] = pb2p[h2];
    }
#pragma unroll
    for (int q = 0; q < 4; ++q) {
#pragma unroll
      for (int r = 0; r < 4; ++r) {
        float sp = 0.f;
#pragma unroll
        for (int u = 0; u < 5; ++u)
          sp += fmaxf(acc2[q][u][r] + b2v[u], 0.f) * w3v[u];
        sp += __shfl_xor(sp, 1);
        sp += __shfl_xor(sp, 2);
        sp += __shfl_xor(sp, 4);
        sp += __shfl_xor(sp, 8);
        if ((lane & 15) == 0) {
          int jl = wj * 64 + q * 16 + ((lane >> 4) << 2) + r;
          *(float*)(smem + 102400 + (jl * 2 + wh) * 4) = sp;
        }
      }
    }
  }
  __syncthreads();
  if (tid < 256) {
    float s = *(const float*)(smem + 102400 + tid * 8) +
              *(const float*)(smem + 102400 + tid * 8 + 4) + pb3[0];
    float v = (mv[i] + mv[tid] + s) * (1.f / 3.f);
    out[i * 256 + tid] = fminf(fmaxf(v, 0.f), 1.f);
  }
}

// ---------------------------------------------------------------------------
extern "C" void kernel_launch(void* const* d_in, const int* in_sizes, int n_in,
                              void* d_out, int out_size, void* d_ws, size_t ws_size,
                              hipStream_t stream) {
  (void)in_sizes; (void)n_in; (void)out_size; (void)ws_size;
  const float* e    = (const float*)d_in[0];
  const int*   sst  = (const int*)d_in[1];
  const int*   swd  = (const int*)d_in[2];
  const float* aW1  = (const float*)d_in[3];
  const float* ab1  = (const float*)d_in[4];
  const float* aW2  = (const float*)d_in[5];
  const float* ab2  = (const float*)d_in[6];
  const float* aW3  = (const float*)d_in[7];
  const float* ab3  = (const float*)d_in[8];
  const float* mW1  = (const float*)d_in[9];
  const float* mb1  = (const float*)d_in[10];
  const float* mW2  = (const float*)d_in[11];
  const float* mb2  = (const float*)d_in[12];
  const float* mW3  = (const float*)d_in[13];
  const float* mb3  = (const float*)d_in[14];
  const float* pW1  = (const float*)d_in[15];
  const float* pb1  = (const float*)d_in[16];
  const float* pW2  = (const float*)d_in[17];
  const float* pb2  = (const float*)d_in[18];
  const float* pW3  = (const float*)d_in[19];
  const float* pb3  = (const float*)d_in[20];
  float* out = (float*)d_out;

  char* ws = (char*)d_ws;
  size_t off = 0;
  auto alloc = [&](size_t bytes) -> char* {
    char* p = ws + off;
    off += (bytes + 255) & ~(size_t)255;
    return p;
  };
  float* attn  = (float*)alloc(2048ULL*4);
  float* g     = (float*)alloc(256ULL*2304*4);
  float* hi    = (float*)alloc(256ULL*160*4);
  float* hj    = (float*)alloc(256ULL*160*4);
  float* mv    = (float*)alloc(256ULL*4);
  float* h1p   = (float*)alloc(4ULL*2048*160*4);
  float* pp    = (float*)alloc(6ULL*256*480*4);
  u16*   aW1Th = (u16*)alloc(160ULL*768*2);
  u16*   aW1Tl = (u16*)alloc(160ULL*768*2);
  u16*   Wcath = (u16*)alloc(480ULL*2304*2);
  u16*   Wcatl = (u16*)alloc(480ULL*2304*2);
  float* aW2p  = (float*)alloc(152ULL*160*4);
  float* mW2p  = (float*)alloc(152ULL*160*4);
  u16*   gkg   = (u16*)alloc(288ULL*256*8*2);
  u16*   Wckg  = (u16*)alloc(288ULL*160*8*2);
  u16*   W2kg  = (u16*)alloc(24ULL*1280*2);
  float* pb1p  = (float*)alloc(160ULL*4);
  float* pb2p  = (float*)alloc(160ULL*4);
  float* w3p   = (float*)alloc(160ULL*4);

  k_prepT<<<dim3(36, 6), 256, 0, stream>>>(mW1, pW1, aW1, aW2, mW2, pW2,
                                           pb1, pb2, pW3,
                                           Wcath, Wcatl, aW1Th, aW1Tl, Wckg,
                                           aW2p, mW2p, W2kg, pb1p, pb2p, w3p);
  k_attn1<<<dim3(64, 4), 256, 0, stream>>>(e, aW1Th, aW1Tl, h1p);
  k_attn2<<<256, 256, 0, stream>>>(h1p, aW2p, ab1, ab2, aW3, ab3, attn);
  k_spans<<<256, 256, 0, stream>>>(e, attn, sst, swd, g, gkg);
  k_span1<<<dim3(16, 3, 6), 128, 0, stream>>>(g, Wcath, Wcatl, pp);
  k_span2r<<<32, 256, 0, stream>>>(pp, mb1, mW2p, mb2, mW3, mb3, hi, hj, mv);
  k_hij7<<<256, 512, 0, stream>>>(g, gkg, Wckg, hi, hj, pb1p,
                                  W2kg, pb2p, w3p, pb3, mv, out);
}

// Round 9
// 131.239 us; speedup vs baseline: 1.6612x; 1.0222x over previous
//
#include <hip/hip_runtime.h>

typedef unsigned short u16;
typedef unsigned int   u32;
typedef short bf16x8 __attribute__((ext_vector_type(8)));
typedef float f32x4  __attribute__((ext_vector_type(4)));

__device__ __forceinline__ u16 f2bf(float f) {
  union { float f; u32 u; } v; v.f = f;
  u32 u = v.u;
  u += 0x7fffu + ((u >> 16) & 1u);   // RNE
  return (u16)(u >> 16);
}

__device__ __forceinline__ void splitbf(float x, u16& hi, u16& lo) {
  hi = f2bf(x);
  union { u32 u; float f; } r; r.u = (u32)hi << 16;
  lo = f2bf(x - r.f);
}

__device__ __forceinline__ float bflo(u32 p) {
  union { u32 u; float f; } v; v.u = p << 16; return v.f;
}
__device__ __forceinline__ float bfhi(u32 p) {
  union { u32 u; float f; } v; v.u = p & 0xffff0000u; return v.f;
}
__device__ __forceinline__ u32 cvtpk(float lo, float hi) {
  u32 r;
  asm("v_cvt_pk_bf16_f32 %0, %1, %2" : "=v"(r) : "v"(lo), "v"(hi));
  return r;
}
__device__ __forceinline__ void gload_lds16(const void* src, void* dst) {
  __builtin_amdgcn_global_load_lds(
      (const __attribute__((address_space(1))) u32*)src,
      (__attribute__((address_space(3))) u32*)dst, 16, 0, 0);
}

// ---------------------------------------------------------------------------
// k_prepT: LDS-tile transpose of the big layer-1 weights + small layouts.
// ---------------------------------------------------------------------------
__global__ __launch_bounds__(256) void k_prepT(
    const float* __restrict__ mW1, const float* __restrict__ pW1,
    const float* __restrict__ aW1, const float* __restrict__ aW2,
    const float* __restrict__ mW2, const float* __restrict__ pW2,
    const float* __restrict__ pb1, const float* __restrict__ pb2,
    const float* __restrict__ pW3,
    u16* __restrict__ Wcath, u16* __restrict__ Wcatl,
    u16* __restrict__ aW1Th, u16* __restrict__ aW1Tl,
    u16* __restrict__ Wckg,
    float* __restrict__ aW2p, float* __restrict__ mW2p,
    u16* __restrict__ W2kg, float* __restrict__ pb1p,
    float* __restrict__ pb2p, float* __restrict__ w3p) {
  __shared__ float ls[64][153];
  const int tid = threadIdx.x;
  const int task = blockIdx.y;
  const int e0 = blockIdx.x * 64;
  if (task == 5) {
    const int stride = 36 * 256;
    const int t0 = blockIdx.x * 256 + tid;
    for (int t = t0; t < 152*160; t += stride) {
      int k = t / 160, h = t % 160;
      bool ok = (k < 150 && h < 150);
      aW2p[t] = ok ? aW2[k*150 + h] : 0.f;
      mW2p[t] = ok ? mW2[k*150 + h] : 0.f;
    }
    for (int t = t0; t < 24*1280; t += stride) {
      int kg = t / 1280, rem = t % 1280;
      int s = rem / 160, n = rem % 160;
      int k = kg*8 + s;
      float v = (k < 150 && n < 150) ? pW2[k*150 + n] : 0.f;
      W2kg[(size_t)kg*1280 + n*8 + s] = f2bf(v);
    }
    for (int t = t0; t < 160; t += stride) {
      pb1p[t] = (t < 150) ? pb1[t] : 0.f;
      pb2p[t] = (t < 150) ? pb2[t] : 0.f;
      w3p[t]  = (t < 150) ? pW3[t] : 0.f;
    }
    return;
  }
  if (task == 3 && e0 >= 768) return;
  const float* src;
  if (task == 0)      src = mW1;
  else if (task == 1) src = pW1;
  else if (task == 2) src = pW1 + (size_t)2304 * 150;
  else if (task == 3) src = aW1;
  else                src = pW1 + (size_t)4608 * 150;
  for (int t = tid; t < 9600; t += 256) {
    int r = t / 150, c = t - r * 150;
    ls[r][c] = src[(size_t)(e0 + r) * 150 + c];
  }
  __syncthreads();
  if (task < 3) {
    u16* dh = Wcath + (size_t)task * 160 * 2304;
    u16* dl = Wcatl + (size_t)task * 160 * 2304;
    for (int t = tid; t < 10240; t += 256) {
      int n = t >> 6, r = t & 63;
      float v = (n < 150) ? ls[r][n] : 0.f;
      u16 h, l; splitbf(v, h, l);
      dh[(size_t)n * 2304 + e0 + r] = h;
      dl[(size_t)n * 2304 + e0 + r] = l;
    }
  } else if (task == 3) {
    for (int t = tid; t < 10240; t += 256) {
      int n = t >> 6, r = t & 63;
      float v = (n < 150) ? ls[r][n] : 0.f;
      u16 h, l; splitbf(v, h, l);
      aW1Th[(size_t)n * 768 + e0 + r] = h;
      aW1Tl[(size_t)n * 768 + e0 + r] = l;
    }
  } else {
    for (int t = tid; t < 10240; t += 256) {
      int n = t >> 6, r = t & 63;
      int e = e0 + r;
      float v = (n < 150) ? ls[r][n] : 0.f;
      Wckg[((size_t)(e >> 3) * 160 + n) * 8 + (e & 7)] = f2bf(v);
    }
  }
}

// ---------------------------------------------------------------------------
// attn layer1 (split-bf16 MFMA GEMM, split-K x4): raw partials
// ---------------------------------------------------------------------------
__global__ __launch_bounds__(256) void k_attn1(
    const float* __restrict__ e, const u16* __restrict__ Wh,
    const u16* __restrict__ Wl, float* __restrict__ h1p) {
  __shared__ u16 lXh[32*64], lXl[32*64], lWh[160*64], lWl[160*64];
  const int tid = threadIdx.x, lane = tid & 63, w = tid >> 6;
  const int wm = w & 1, wh = w >> 1;
  const int m0 = blockIdx.x * 32;
  const int z  = blockIdx.y;
  f32x4 acc[5] = {};
  for (int e0 = z*192; e0 < (z+1)*192; e0 += 64) {
    {
      int r = tid >> 3, ec = tid & 7;
      const float* src = e + (size_t)(m0 + r)*768 + e0 + ec*8;
      float4 x0 = *(const float4*)src, x1 = *(const float4*)(src + 4);
      float xs[8] = {x0.x,x0.y,x0.z,x0.w,x1.x,x1.y,x1.z,x1.w};
      u16 hb[8], lb[8];
#pragma unroll
      for (int q = 0; q < 8; ++q) splitbf(xs[q], hb[q], lb[q]);
      int off = (r*128 + ec*16) ^ ((r & 7) << 4);
      *(uint4*)((char*)lXh + off) = make_uint4(
        (u32)hb[0]|((u32)hb[1]<<16), (u32)hb[2]|((u32)hb[3]<<16),
        (u32)hb[4]|((u32)hb[5]<<16), (u32)hb[6]|((u32)hb[7]<<16));
      *(uint4*)((char*)lXl + off) = make_uint4(
        (u32)lb[0]|((u32)lb[1]<<16), (u32)lb[2]|((u32)lb[3]<<16),
        (u32)lb[4]|((u32)lb[5]<<16), (u32)lb[6]|((u32)lb[7]<<16));
    }
#pragma unroll
    for (int t = 0; t < 5; ++t) {
      int c = tid + t*256;
      int h = c >> 3, ec = c & 7;
      int off = (h*128 + ec*16) ^ ((h & 7) << 4);
      *(uint4*)((char*)lWh + off) = *(const uint4*)(Wh + (size_t)h*768 + e0 + ec*8);
      *(uint4*)((char*)lWl + off) = *(const uint4*)(Wl + (size_t)h*768 + e0 + ec*8);
    }
    __syncthreads();
#pragma unroll
    for (int ks = 0; ks < 2; ++ks) {
      int eb = ks*64 + ((lane >> 4) << 4);
      int ar = wm*16 + (lane & 15);
      bf16x8 Ah = *(const bf16x8*)((const char*)lXh + ((ar*128 + eb) ^ ((ar & 7) << 4)));
      bf16x8 Al = *(const bf16x8*)((const char*)lXl + ((ar*128 + eb) ^ ((ar & 7) << 4)));
#pragma unroll
      for (int t = 0; t < 5; ++t) {
        int br = wh*80 + t*16 + (lane & 15);
        bf16x8 Bh = *(const bf16x8*)((const char*)lWh + ((br*128 + eb) ^ ((br & 7) << 4)));
        bf16x8 Bl = *(const bf16x8*)((const char*)lWl + ((br*128 + eb) ^ ((br & 7) << 4)));
        acc[t] = __builtin_amdgcn_mfma_f32_16x16x32_bf16(Ah, Bh, acc[t], 0, 0, 0);
        acc[t] = __builtin_amdgcn_mfma_f32_16x16x32_bf16(Al, Bh, acc[t], 0, 0, 0);
        acc[t] = __builtin_amdgcn_mfma_f32_16x16x32_bf16(Ah, Bl, acc[t], 0, 0, 0);
      }
    }
    __syncthreads();
  }
#pragma unroll
  for (int t = 0; t < 5; ++t) {
    int n = wh*80 + t*16 + (lane & 15);
#pragma unroll
    for (int r = 0; r < 4; ++r) {
      int m = m0 + wm*16 + ((lane >> 4) << 2) + r;
      h1p[((size_t)z*2048 + m)*160 + n] = acc[t][r];
    }
  }
}

// ---------------------------------------------------------------------------
// attn layers 2+3 (sums 4 split-K partials, bias+relu, then MLP tail)
// ---------------------------------------------------------------------------
__global__ __launch_bounds__(256) void k_attn2(
    const float* __restrict__ h1p, const float* __restrict__ W2p,
    const float* __restrict__ b1, const float* __restrict__ b2,
    const float* __restrict__ w3, const float* __restrict__ b3,
    float* __restrict__ attn) {
  __shared__ float hs[8][160];
  const int tid = threadIdx.x;
  const int t0 = blockIdx.x * 8;
  for (int idx = tid; idx < 1280; idx += 256) {
    int m = idx / 160, h = idx - m * 160;
    float s = 0.f;
#pragma unroll
    for (int z = 0; z < 4; ++z)
      s += h1p[((size_t)z*2048 + t0 + m)*160 + h];
    hs[m][h] = (h < 150) ? fmaxf(s + b1[h], 0.f) : 0.f;
  }
  __syncthreads();
  const int sp = tid >> 5, hb = tid & 31;
  float a2[5] = {0.f,0.f,0.f,0.f,0.f};
  for (int k = 0; k < 150; ++k) {
    float x = hs[sp][k];
#pragma unroll
    for (int q = 0; q < 5; ++q) a2[q] = fmaf(x, W2p[k*160 + hb + 32*q], a2[q]);
  }
  float p = 0.f;
#pragma unroll
  for (int q = 0; q < 5; ++q) {
    int h = hb + 32*q;
    if (h < 150) p += fmaxf(a2[q] + b2[h], 0.f) * w3[h];
  }
  p += __shfl_xor(p, 16, 32);
  p += __shfl_xor(p, 8, 32);
  p += __shfl_xor(p, 4, 32);
  p += __shfl_xor(p, 2, 32);
  p += __shfl_xor(p, 1, 32);
  if (hb == 0) attn[t0 + sp] = p + b3[0];
}

// ---------------------------------------------------------------------------
// g[s] = [e[start], e[end], span_sum]; also writes gkg (k-grouped bf16)
// ---------------------------------------------------------------------------
__global__ __launch_bounds__(256) void k_spans(
    const float* __restrict__ e, const float* __restrict__ attn,
    const int* __restrict__ sstart, const int* __restrict__ swidth,
    float* __restrict__ g, u16* __restrict__ gkg) {
  const int s = blockIdx.x;
  int st = sstart[s];
  int en = st + swidth[s];
  if (en > 2047) en = 2047;
  if (en < 0) en = 0;
  const int tid = threadIdx.x;
  for (int d = tid; d < 768; d += 256) {
    float v0 = e[(size_t)st*768 + d];
    float v1 = e[(size_t)en*768 + d];
    float acc = 0.f;
    for (int t = st; t <= en; ++t) acc += e[(size_t)t*768 + d] * attn[t];
    g[s*2304 + d]        = v0;
    g[s*2304 + 768 + d]  = v1;
    g[s*2304 + 1536 + d] = acc;
    int c0 = d, c1 = 768 + d, c2 = 1536 + d;
    gkg[((size_t)(c0>>3)*256 + s)*8 + (c0&7)] = f2bf(v0);
    gkg[((size_t)(c1>>3)*256 + s)*8 + (c1&7)] = f2bf(v1);
    gkg[((size_t)(c2>>3)*256 + s)*8 + (c2&7)] = f2bf(acc);
  }
}

// ---------------------------------------------------------------------------
// span layer1 (split-bf16 MFMA GEMM, split-K x6): raw partials
// ---------------------------------------------------------------------------
__global__ __launch_bounds__(128) void k_span1(
    const float* __restrict__ g, const u16* __restrict__ Wh,
    const u16* __restrict__ Wl, float* __restrict__ pp) {
  __shared__ u16 lXh[16*64], lXl[16*64], lWh[160*64], lWl[160*64];
  const int tid = threadIdx.x, lane = tid & 63;
  const int wh = tid >> 6;
  const int m0 = blockIdx.x * 16;
  const int n0 = blockIdx.y * 160;
  const int z  = blockIdx.z;
  f32x4 acc[5] = {};
  for (int e0 = z*384; e0 < (z+1)*384; e0 += 64) {
    {
      int r = tid >> 3, ec = tid & 7;
      const float* src = g + (size_t)(m0 + r)*2304 + e0 + ec*8;
      float4 x0 = *(const float4*)src, x1 = *(const float4*)(src + 4);
      float xs[8] = {x0.x,x0.y,x0.z,x0.w,x1.x,x1.y,x1.z,x1.w};
      u16 hb[8], lb[8];
#pragma unroll
      for (int q = 0; q < 8; ++q) splitbf(xs[q], hb[q], lb[q]);
      int off = (r*128 + ec*16) ^ ((r & 7) << 4);
      *(uint4*)((char*)lXh + off) = make_uint4(
        (u32)hb[0]|((u32)hb[1]<<16), (u32)hb[2]|((u32)hb[3]<<16),
        (u32)hb[4]|((u32)hb[5]<<16), (u32)hb[6]|((u32)hb[7]<<16));
      *(uint4*)((char*)lXl + off) = make_uint4(
        (u32)lb[0]|((u32)lb[1]<<16), (u32)lb[2]|((u32)lb[3]<<16),
        (u32)lb[4]|((u32)lb[5]<<16), (u32)lb[6]|((u32)lb[7]<<16));
    }
#pragma unroll
    for (int t = 0; t < 10; ++t) {
      int c = tid + t*128;
      int h = c >> 3, ec = c & 7;
      int off = (h*128 + ec*16) ^ ((h & 7) << 4);
      *(uint4*)((char*)lWh + off) = *(const uint4*)(Wh + (size_t)(n0 + h)*2304 + e0 + ec*8);
      *(uint4*)((char*)lWl + off) = *(const uint4*)(Wl + (size_t)(n0 + h)*2304 + e0 + ec*8);
    }
    __syncthreads();
#pragma unroll
    for (int ks = 0; ks < 2; ++ks) {
      int eb = ks*64 + ((lane >> 4) << 4);
      int ar = lane & 15;
      bf16x8 Ah = *(const bf16x8*)((const char*)lXh + ((ar*128 + eb) ^ ((ar & 7) << 4)));
      bf16x8 Al = *(const bf16x8*)((const char*)lXl + ((ar*128 + eb) ^ ((ar & 7) << 4)));
#pragma unroll
      for (int t = 0; t < 5; ++t) {
        int br = wh*80 + t*16 + (lane & 15);
        bf16x8 Bh = *(const bf16x8*)((const char*)lWh + ((br*128 + eb) ^ ((br & 7) << 4)));
        bf16x8 Bl = *(const bf16x8*)((const char*)lWl + ((br*128 + eb) ^ ((br & 7) << 4)));
        acc[t] = __builtin_amdgcn_mfma_f32_16x16x32_bf16(Ah, Bh, acc[t], 0, 0, 0);
        acc[t] = __builtin_amdgcn_mfma_f32_16x16x32_bf16(Al, Bh, acc[t], 0, 0, 0);
        acc[t] = __builtin_amdgcn_mfma_f32_16x16x32_bf16(Ah, Bl, acc[t], 0, 0, 0);
      }
    }
    __syncthreads();
  }
#pragma unroll
  for (int t = 0; t < 5; ++t) {
    int nc = n0 + wh*80 + t*16 + (lane & 15);
#pragma unroll
    for (int r = 0; r < 4; ++r) {
      int m = m0 + ((lane >> 4) << 2) + r;
      pp[((size_t)z*256 + m)*480 + nc] = acc[t][r];
    }
  }
}

// ---------------------------------------------------------------------------
// span reduce + layers 2+3 (merged)
// ---------------------------------------------------------------------------
__global__ __launch_bounds__(256) void k_span2r(
    const float* __restrict__ pp, const float* __restrict__ mb1,
    const float* __restrict__ W2p, const float* __restrict__ b2,
    const float* __restrict__ w3, const float* __restrict__ b3,
    float* __restrict__ hi, float* __restrict__ hj, float* __restrict__ mo) {
  __shared__ float hs[8][160];
  const int tid = threadIdx.x;
  const int s0 = blockIdx.x * 8;
  for (int idx = tid; idx < 3840; idx += 256) {
    int mr = idx / 480, n = idx - mr * 480;
    int m = s0 + mr;
    float s = 0.f;
#pragma unroll
    for (int z = 0; z < 6; ++z) s += pp[((size_t)z*256 + m)*480 + n];
    if (n < 160)      hs[mr][n] = (n < 150) ? fmaxf(s + mb1[n], 0.f) : 0.f;
    else if (n < 320) hi[m*160 + n - 160] = s;
    else              hj[m*160 + n - 320] = s;
  }
  __syncthreads();
  const int sp = tid >> 5, hb = tid & 31;
  float a2[5] = {0.f,0.f,0.f,0.f,0.f};
  for (int k = 0; k < 150; ++k) {
    float x = hs[sp][k];
#pragma unroll
    for (int q = 0; q < 5; ++q) a2[q] = fmaf(x, W2p[k*160 + hb + 32*q], a2[q]);
  }
  float p = 0.f;
#pragma unroll
  for (int q = 0; q < 5; ++q) {
    int h = hb + 32*q;
    if (h < 150) p += fmaxf(a2[q] + b2[h], 0.f) * w3[h];
  }
  p += __shfl_xor(p, 16, 32);
  p += __shfl_xor(p, 8, 32);
  p += __shfl_xor(p, 4, 32);
  p += __shfl_xor(p, 2, 32);
  p += __shfl_xor(p, 1, 32);
  if (hb == 0) mo[s0 + sp] = p + b3[0];
}

// ---------------------------------------------------------------------------
// k_hij8: fused big einsum + pairwise MLP. ONE block per i (256 blocks,
// 1024 threads = 16 waves as wj(8) x wh(2); wave tile 32j x 80h, j-span 256).
// 4 waves/SIMD (vs 2 in k_hij7) to hide the per-wave serial chain
// (ds_read -> MFMA -> loads -> cvt -> ds_write -> barrier).
// A GLOBAL->VGPR from gkg; B' (g[i].*Wc) dbuf LDS, reg-staged cvt;
// single raw s_barrier + lgkmcnt(0)-only wait per chunk (counted vmcnt).
// LDS: B' dbuf 2x20480 @0; then h1' [20kg][256j][8] @0 (80K);
//      B2 @81920 (20K); red @102400. Total 104448.
// ---------------------------------------------------------------------------
__global__ __launch_bounds__(1024, 1) void k_hij8(
    const float* __restrict__ g, const u16* __restrict__ gkg,
    const u16* __restrict__ Wckg, const float* __restrict__ hi,
    const float* __restrict__ hj, const float* __restrict__ pb1p,
    const u16* __restrict__ W2kg, const float* __restrict__ pb2p,
    const float* __restrict__ w3p, const float* __restrict__ pb3,
    const float* __restrict__ mv, float* __restrict__ out) {
  __shared__ __align__(16) char smem[104448];
  const int tid = threadIdx.x, lane = tid & 63, w = tid >> 6;
  const int wj = w & 7, wh = w >> 3;
  const int i = blockIdx.x;
  const float* grow = g + (size_t)i * 2304;

  f32x4 acc[2][5] = {};
  bf16x8 afC[4];
  uint4 wcR[2];
  float4 gA[2], gB[2];

  // A fragment base: granule (kg, j) at ((t*8+kg)*256 + j)*8 elems
  const u16* pA = gkg + (((lane >> 4) * 256) + wj * 32 + (lane & 15)) * 8;
  const int ep0 = (tid / 160) * 8;
  const int ep1 = ((tid + 1024) / 160) * 8;
  const int bB = (((lane >> 4) * 160) + wh * 80 + (lane & 15)) * 16;

  auto loadA = [&](int t) {
    const u16* p = pA + (size_t)t * 16384;
#pragma unroll
    for (int ks = 0; ks < 2; ++ks)
#pragma unroll
      for (int q = 0; q < 2; ++q)
        afC[ks * 2 + q] = *(const bf16x8*)(p + ks * 8192 + q * 128);
  };
  auto loadB = [&](int t) {
    const u16* wp = Wckg + (size_t)t * 10240;
    const float* gp = grow + t * 64;
    wcR[0] = *(const uint4*)(wp + (size_t)tid * 8);
    gA[0] = *(const float4*)(gp + ep0); gB[0] = *(const float4*)(gp + ep0 + 4);
    if (tid < 256) {
      wcR[1] = *(const uint4*)(wp + (size_t)(tid + 1024) * 8);
      gA[1] = *(const float4*)(gp + ep1); gB[1] = *(const float4*)(gp + ep1 + 4);
    }
  };
  auto writeB = [&](int buf) {
    char* base = smem + buf * 20480;
    {
      uint4 v = wcR[0]; float4 ga = gA[0], gb = gB[0];
      uint4 r;
      r.x = cvtpk(bflo(v.x) * ga.x, bfhi(v.x) * ga.y);
      r.y = cvtpk(bflo(v.y) * ga.z, bfhi(v.y) * ga.w);
      r.z = cvtpk(bflo(v.z) * gb.x, bfhi(v.z) * gb.y);
      r.w = cvtpk(bflo(v.w) * gb.z, bfhi(v.w) * gb.w);
      *(uint4*)(base + tid * 16) = r;
    }
    if (tid < 256) {
      uint4 v = wcR[1]; float4 ga = gA[1], gb = gB[1];
      uint4 r;
      r.x = cvtpk(bflo(v.x) * ga.x, bfhi(v.x) * ga.y);
      r.y = cvtpk(bflo(v.y) * ga.z, bfhi(v.y) * ga.w);
      r.z = cvtpk(bflo(v.z) * gb.x, bfhi(v.z) * gb.y);
      r.w = cvtpk(bflo(v.w) * gb.z, bfhi(v.w) * gb.w);
      *(uint4*)(base + (tid + 1024) * 16) = r;
    }
  };

  // prologue: loadB first (older) so writeB's wait leaves loadA outstanding
  loadB(0);
  loadA(0);
  writeB(0);
  asm volatile("s_waitcnt lgkmcnt(0)" ::: "memory");
  __builtin_amdgcn_s_barrier();
  __builtin_amdgcn_sched_barrier(0);

  for (int t = 0; t < 36; ++t) {
    const int buf = t & 1;
    if (t < 35) loadB(t + 1);
    const char* Bb = smem + buf * 20480;
    __builtin_amdgcn_s_setprio(1);
#pragma unroll
    for (int ks = 0; ks < 2; ++ks) {
#pragma unroll
      for (int u = 0; u < 5; ++u) {
        bf16x8 bfr = *(const bf16x8*)(Bb + bB + ks * 10240 + u * 256);
#pragma unroll
        for (int q = 0; q < 2; ++q)
          acc[q][u] = __builtin_amdgcn_mfma_f32_16x16x32_bf16(
              afC[ks * 2 + q], bfr, acc[q][u], 0, 0, 0);
      }
    }
    __builtin_amdgcn_s_setprio(0);
    if (t < 35) { loadA(t + 1); writeB(buf ^ 1); }
    // this wave's ds ops only; global loads legally span the barrier
    asm volatile("s_waitcnt lgkmcnt(0)" ::: "memory");
    __builtin_amdgcn_s_barrier();
    __builtin_amdgcn_sched_barrier(0);
  }

  // ---- epilogue1: h1 = relu(hij + hi + hj + pb1) -> LDS bf16 [20][256][8] --
  {
    float hib[5];
#pragma unroll
    for (int u = 0; u < 5; ++u) {
      int h = wh * 80 + u * 16 + (lane & 15);
      hib[u] = hi[i * 160 + h] + pb1p[h];
    }
#pragma unroll
    for (int q = 0; q < 2; ++q) {
      int jl = wj * 32 + q * 16 + ((lane >> 4) << 2);
#pragma unroll
      for (int r = 0; r < 4; ++r) {
        const float* hjr = hj + (size_t)(jl + r) * 160;
#pragma unroll
        for (int u = 0; u < 5; ++u) {
          int h = wh * 80 + u * 16 + (lane & 15);
          float v = fmaxf(acc[q][u][r] + hib[u] + hjr[h], 0.f);
          *(u16*)(smem + ((h >> 3) * 256 + jl + r) * 16 + (h & 7) * 2) = f2bf(v);
        }
      }
    }
  }
  __syncthreads();

  // ---- GEMM2: h2 = h1' @ W2 (K=160), 3 chunks (8,8,4 kgrps) ----
  f32x4 acc2[2][5] = {};
  for (int c = 0; c < 3; ++c) {
    const int G64 = (c < 2) ? 20 : 10;
    for (int g0 = w; g0 < G64; g0 += 16) {
      const u16* src = W2kg + ((size_t)c * 1280 + g0 * 64 + lane) * 8;
      gload_lds16(src, smem + 81920 + g0 * 1024);
    }
    __syncthreads();
    const int nks = (c < 2) ? 2 : 1;
    for (int ks = 0; ks < nks; ++ks) {
      const int kl = ks * 4 + (lane >> 4);
      bf16x8 af2[2];
#pragma unroll
      for (int q = 0; q < 2; ++q)
        af2[q] = *(const bf16x8*)(smem + ((c * 8 + kl) * 256 + wj * 32 + q * 16 + (lane & 15)) * 16);
#pragma unroll
      for (int u = 0; u < 5; ++u) {
        bf16x8 b2 = *(const bf16x8*)(smem + 81920 + (kl * 160 + wh * 80 + u * 16 + (lane & 15)) * 16);
#pragma unroll
        for (int q = 0; q < 2; ++q)
          acc2[q][u] = __builtin_amdgcn_mfma_f32_16x16x32_bf16(af2[q], b2, acc2[q][u], 0, 0, 0);
      }
    }
    __syncthreads();
  }

  // ---- epilogue2: s = relu(h2 + pb2).w3 ; out = clip((mi+mj+s)/3) ----
  {
    float w3v[5], b2v[5];
#pragma unroll
    for (int u = 0; u < 5; ++u) {
      int h2 = wh * 80 + u * 16 + (lane & 15);
      w3v[u] = w3p[h2]; b2v[u] = pb2p[h2];
    }
#pragma unroll
    for (int q = 0; q < 2; ++q) {
#pragma unroll
      for (int r = 0; r < 4; ++r) {
        float sp = 0.f;
#pragma unroll
        for (int u = 0; u < 5; ++u)
          sp += fmaxf(acc2[q][u][r] + b2v[u], 0.f) * w3v[u];
        sp += __shfl_xor(sp, 1);
        sp += __shfl_xor(sp, 2);
        sp += __shfl_xor(sp, 4);
        sp += __shfl_xor(sp, 8);
        if ((lane & 15) == 0) {
          int jl = wj * 32 + q * 16 + ((lane >> 4) << 2) + r;
          *(float*)(smem + 102400 + (jl * 2 + wh) * 4) = sp;
        }
      }
    }
  }
  __syncthreads();
  if (tid < 256) {
    float s = *(const float*)(smem + 102400 + tid * 8) +
              *(const float*)(smem + 102400 + tid * 8 + 4) + pb3[0];
    float v = (mv[i] + mv[tid] + s) * (1.f / 3.f);
    out[i * 256 + tid] = fminf(fmaxf(v, 0.f), 1.f);
  }
}

// ---------------------------------------------------------------------------
extern "C" void kernel_launch(void* const* d_in, const int* in_sizes, int n_in,
                              void* d_out, int out_size, void* d_ws, size_t ws_size,
                              hipStream_t stream) {
  (void)in_sizes; (void)n_in; (void)out_size; (void)ws_size;
  const float* e    = (const float*)d_in[0];
  const int*   sst  = (const int*)d_in[1];
  const int*   swd  = (const int*)d_in[2];
  const float* aW1  = (const float*)d_in[3];
  const float* ab1  = (const float*)d_in[4];
  const float* aW2  = (const float*)d_in[5];
  const float* ab2  = (const float*)d_in[6];
  const float* aW3  = (const float*)d_in[7];
  const float* ab3  = (const float*)d_in[8];
  const float* mW1  = (const float*)d_in[9];
  const float* mb1  = (const float*)d_in[10];
  const float* mW2  = (const float*)d_in[11];
  const float* mb2  = (const float*)d_in[12];
  const float* mW3  = (const float*)d_in[13];
  const float* mb3  = (const float*)d_in[14];
  const float* pW1  = (const float*)d_in[15];
  const float* pb1  = (const float*)d_in[16];
  const float* pW2  = (const float*)d_in[17];
  const float* pb2  = (const float*)d_in[18];
  const float* pW3  = (const float*)d_in[19];
  const float* pb3  = (const float*)d_in[20];
  float* out = (float*)d_out;

  char* ws = (char*)d_ws;
  size_t off = 0;
  auto alloc = [&](size_t bytes) -> char* {
    char* p = ws + off;
    off += (bytes + 255) & ~(size_t)255;
    return p;
  };
  float* attn  = (float*)alloc(2048ULL*4);
  float* g     = (float*)alloc(256ULL*2304*4);
  float* hi    = (float*)alloc(256ULL*160*4);
  float* hj    = (float*)alloc(256ULL*160*4);
  float* mv    = (float*)alloc(256ULL*4);
  float* h1p   = (float*)alloc(4ULL*2048*160*4);
  float* pp    = (float*)alloc(6ULL*256*480*4);
  u16*   aW1Th = (u16*)alloc(160ULL*768*2);
  u16*   aW1Tl = (u16*)alloc(160ULL*768*2);
  u16*   Wcath = (u16*)alloc(480ULL*2304*2);
  u16*   Wcatl = (u16*)alloc(480ULL*2304*2);
  float* aW2p  = (float*)alloc(152ULL*160*4);
  float* mW2p  = (float*)alloc(152ULL*160*4);
  u16*   gkg   = (u16*)alloc(288ULL*256*8*2);
  u16*   Wckg  = (u16*)alloc(288ULL*160*8*2);
  u16*   W2kg  = (u16*)alloc(24ULL*1280*2);
  float* pb1p  = (float*)alloc(160ULL*4);
  float* pb2p  = (float*)alloc(160ULL*4);
  float* w3p   = (float*)alloc(160ULL*4);

  k_prepT<<<dim3(36, 6), 256, 0, stream>>>(mW1, pW1, aW1, aW2, mW2, pW2,
                                           pb1, pb2, pW3,
                                           Wcath, Wcatl, aW1Th, aW1Tl, Wckg,
                                           aW2p, mW2p, W2kg, pb1p, pb2p, w3p);
  k_attn1<<<dim3(64, 4), 256, 0, stream>>>(e, aW1Th, aW1Tl, h1p);
  k_attn2<<<256, 256, 0, stream>>>(h1p, aW2p, ab1, ab2, aW3, ab3, attn);
  k_spans<<<256, 256, 0, stream>>>(e, attn, sst, swd, g, gkg);
  k_span1<<<dim3(16, 3, 6), 128, 0, stream>>>(g, Wcath, Wcatl, pp);
  k_span2r<<<32, 256, 0, stream>>>(pp, mb1, mW2p, mb2, mW3, mb3, hi, hj, mv);
  k_hij8<<<256, 1024, 0, stream>>>(g, gkg, Wckg, hi, hj, pb1p,
                                   W2kg, pb2p, w3p, pb3, mv, out);
}

// Round 10
// 130.996 us; speedup vs baseline: 1.6643x; 1.0019x over previous
//
#include <hip/hip_runtime.h>

typedef unsigned short u16;
typedef unsigned int   u32;
typedef short bf16x8 __attribute__((ext_vector_type(8)));
typedef float f32x4  __attribute__((ext_vector_type(4)));

__device__ __forceinline__ u16 f2bf(float f) {
  union { float f; u32 u; } v; v.f = f;
  u32 u = v.u;
  u += 0x7fffu + ((u >> 16) & 1u);   // RNE
  return (u16)(u >> 16);
}

__device__ __forceinline__ void splitbf(float x, u16& hi, u16& lo) {
  hi = f2bf(x);
  union { u32 u; float f; } r; r.u = (u32)hi << 16;
  lo = f2bf(x - r.f);
}

__device__ __forceinline__ float bflo(u32 p) {
  union { u32 u; float f; } v; v.u = p << 16; return v.f;
}
__device__ __forceinline__ float bfhi(u32 p) {
  union { u32 u; float f; } v; v.u = p & 0xffff0000u; return v.f;
}
__device__ __forceinline__ u32 cvtpk(float lo, float hi) {
  u32 r;
  asm("v_cvt_pk_bf16_f32 %0, %1, %2" : "=v"(r) : "v"(lo), "v"(hi));
  return r;
}
__device__ __forceinline__ void gload_lds16(const void* src, void* dst) {
  __builtin_amdgcn_global_load_lds(
      (const __attribute__((address_space(1))) u32*)src,
      (__attribute__((address_space(3))) u32*)dst, 16, 0, 0);
}

// ---------------------------------------------------------------------------
// k_prepT: LDS-tile transpose of the big layer-1 weights + small layouts.
// ---------------------------------------------------------------------------
__global__ __launch_bounds__(256) void k_prepT(
    const float* __restrict__ mW1, const float* __restrict__ pW1,
    const float* __restrict__ aW1, const float* __restrict__ aW2,
    const float* __restrict__ mW2, const float* __restrict__ pW2,
    const float* __restrict__ pb1, const float* __restrict__ pb2,
    const float* __restrict__ pW3,
    u16* __restrict__ Wcath, u16* __restrict__ Wcatl,
    u16* __restrict__ aW1Th, u16* __restrict__ aW1Tl,
    u16* __restrict__ Wckg,
    float* __restrict__ aW2p, float* __restrict__ mW2p,
    u16* __restrict__ W2kg, float* __restrict__ pb1p,
    float* __restrict__ pb2p, float* __restrict__ w3p) {
  __shared__ float ls[64][153];
  const int tid = threadIdx.x;
  const int task = blockIdx.y;
  const int e0 = blockIdx.x * 64;
  if (task == 5) {
    const int stride = 36 * 256;
    const int t0 = blockIdx.x * 256 + tid;
    for (int t = t0; t < 152*160; t += stride) {
      int k = t / 160, h = t % 160;
      bool ok = (k < 150 && h < 150);
      aW2p[t] = ok ? aW2[k*150 + h] : 0.f;
      mW2p[t] = ok ? mW2[k*150 + h] : 0.f;
    }
    for (int t = t0; t < 24*1280; t += stride) {
      int kg = t / 1280, rem = t % 1280;
      int s = rem / 160, n = rem % 160;
      int k = kg*8 + s;
      float v = (k < 150 && n < 150) ? pW2[k*150 + n] : 0.f;
      W2kg[(size_t)kg*1280 + n*8 + s] = f2bf(v);
    }
    for (int t = t0; t < 160; t += stride) {
      pb1p[t] = (t < 150) ? pb1[t] : 0.f;
      pb2p[t] = (t < 150) ? pb2[t] : 0.f;
      w3p[t]  = (t < 150) ? pW3[t] : 0.f;
    }
    return;
  }
  if (task == 3 && e0 >= 768) return;
  const float* src;
  if (task == 0)      src = mW1;
  else if (task == 1) src = pW1;
  else if (task == 2) src = pW1 + (size_t)2304 * 150;
  else if (task == 3) src = aW1;
  else                src = pW1 + (size_t)4608 * 150;
  for (int t = tid; t < 9600; t += 256) {
    int r = t / 150, c = t - r * 150;
    ls[r][c] = src[(size_t)(e0 + r) * 150 + c];
  }
  __syncthreads();
  if (task < 3) {
    u16* dh = Wcath + (size_t)task * 160 * 2304;
    u16* dl = Wcatl + (size_t)task * 160 * 2304;
    for (int t = tid; t < 10240; t += 256) {
      int n = t >> 6, r = t & 63;
      float v = (n < 150) ? ls[r][n] : 0.f;
      u16 h, l; splitbf(v, h, l);
      dh[(size_t)n * 2304 + e0 + r] = h;
      dl[(size_t)n * 2304 + e0 + r] = l;
    }
  } else if (task == 3) {
    for (int t = tid; t < 10240; t += 256) {
      int n = t >> 6, r = t & 63;
      float v = (n < 150) ? ls[r][n] : 0.f;
      u16 h, l; splitbf(v, h, l);
      aW1Th[(size_t)n * 768 + e0 + r] = h;
      aW1Tl[(size_t)n * 768 + e0 + r] = l;
    }
  } else {
    for (int t = tid; t < 10240; t += 256) {
      int n = t >> 6, r = t & 63;
      int e = e0 + r;
      float v = (n < 150) ? ls[r][n] : 0.f;
      Wckg[((size_t)(e >> 3) * 160 + n) * 8 + (e & 7)] = f2bf(v);
    }
  }
}

// ---------------------------------------------------------------------------
// attn layer1 (split-bf16 MFMA GEMM, split-K x4): raw partials
// ---------------------------------------------------------------------------
__global__ __launch_bounds__(256) void k_attn1(
    const float* __restrict__ e, const u16* __restrict__ Wh,
    const u16* __restrict__ Wl, float* __restrict__ h1p) {
  __shared__ u16 lXh[32*64], lXl[32*64], lWh[160*64], lWl[160*64];
  const int tid = threadIdx.x, lane = tid & 63, w = tid >> 6;
  const int wm = w & 1, wh = w >> 1;
  const int m0 = blockIdx.x * 32;
  const int z  = blockIdx.y;
  f32x4 acc[5] = {};
  for (int e0 = z*192; e0 < (z+1)*192; e0 += 64) {
    {
      int r = tid >> 3, ec = tid & 7;
      const float* src = e + (size_t)(m0 + r)*768 + e0 + ec*8;
      float4 x0 = *(const float4*)src, x1 = *(const float4*)(src + 4);
      float xs[8] = {x0.x,x0.y,x0.z,x0.w,x1.x,x1.y,x1.z,x1.w};
      u16 hb[8], lb[8];
#pragma unroll
      for (int q = 0; q < 8; ++q) splitbf(xs[q], hb[q], lb[q]);
      int off = (r*128 + ec*16) ^ ((r & 7) << 4);
      *(uint4*)((char*)lXh + off) = make_uint4(
        (u32)hb[0]|((u32)hb[1]<<16), (u32)hb[2]|((u32)hb[3]<<16),
        (u32)hb[4]|((u32)hb[5]<<16), (u32)hb[6]|((u32)hb[7]<<16));
      *(uint4*)((char*)lXl + off) = make_uint4(
        (u32)lb[0]|((u32)lb[1]<<16), (u32)lb[2]|((u32)lb[3]<<16),
        (u32)lb[4]|((u32)lb[5]<<16), (u32)lb[6]|((u32)lb[7]<<16));
    }
#pragma unroll
    for (int t = 0; t < 5; ++t) {
      int c = tid + t*256;
      int h = c >> 3, ec = c & 7;
      int off = (h*128 + ec*16) ^ ((h & 7) << 4);
      *(uint4*)((char*)lWh + off) = *(const uint4*)(Wh + (size_t)h*768 + e0 + ec*8);
      *(uint4*)((char*)lWl + off) = *(const uint4*)(Wl + (size_t)h*768 + e0 + ec*8);
    }
    __syncthreads();
#pragma unroll
    for (int ks = 0; ks < 2; ++ks) {
      int eb = ks*64 + ((lane >> 4) << 4);
      int ar = wm*16 + (lane & 15);
      bf16x8 Ah = *(const bf16x8*)((const char*)lXh + ((ar*128 + eb) ^ ((ar & 7) << 4)));
      bf16x8 Al = *(const bf16x8*)((const char*)lXl + ((ar*128 + eb) ^ ((ar & 7) << 4)));
#pragma unroll
      for (int t = 0; t < 5; ++t) {
        int br = wh*80 + t*16 + (lane & 15);
        bf16x8 Bh = *(const bf16x8*)((const char*)lWh + ((br*128 + eb) ^ ((br & 7) << 4)));
        bf16x8 Bl = *(const bf16x8*)((const char*)lWl + ((br*128 + eb) ^ ((br & 7) << 4)));
        acc[t] = __builtin_amdgcn_mfma_f32_16x16x32_bf16(Ah, Bh, acc[t], 0, 0, 0);
        acc[t] = __builtin_amdgcn_mfma_f32_16x16x32_bf16(Al, Bh, acc[t], 0, 0, 0);
        acc[t] = __builtin_amdgcn_mfma_f32_16x16x32_bf16(Ah, Bl, acc[t], 0, 0, 0);
      }
    }
    __syncthreads();
  }
#pragma unroll
  for (int t = 0; t < 5; ++t) {
    int n = wh*80 + t*16 + (lane & 15);
#pragma unroll
    for (int r = 0; r < 4; ++r) {
      int m = m0 + wm*16 + ((lane >> 4) << 2) + r;
      h1p[((size_t)z*2048 + m)*160 + n] = acc[t][r];
    }
  }
}

// ---------------------------------------------------------------------------
// attn layers 2+3 (sums 4 split-K partials, bias+relu, then MLP tail)
// ---------------------------------------------------------------------------
__global__ __launch_bounds__(256) void k_attn2(
    const float* __restrict__ h1p, const float* __restrict__ W2p,
    const float* __restrict__ b1, const float* __restrict__ b2,
    const float* __restrict__ w3, const float* __restrict__ b3,
    float* __restrict__ attn) {
  __shared__ float hs[8][160];
  const int tid = threadIdx.x;
  const int t0 = blockIdx.x * 8;
  for (int idx = tid; idx < 1280; idx += 256) {
    int m = idx / 160, h = idx - m * 160;
    float s = 0.f;
#pragma unroll
    for (int z = 0; z < 4; ++z)
      s += h1p[((size_t)z*2048 + t0 + m)*160 + h];
    hs[m][h] = (h < 150) ? fmaxf(s + b1[h], 0.f) : 0.f;
  }
  __syncthreads();
  const int sp = tid >> 5, hb = tid & 31;
  float a2[5] = {0.f,0.f,0.f,0.f,0.f};
  for (int k = 0; k < 150; ++k) {
    float x = hs[sp][k];
#pragma unroll
    for (int q = 0; q < 5; ++q) a2[q] = fmaf(x, W2p[k*160 + hb + 32*q], a2[q]);
  }
  float p = 0.f;
#pragma unroll
  for (int q = 0; q < 5; ++q) {
    int h = hb + 32*q;
    if (h < 150) p += fmaxf(a2[q] + b2[h], 0.f) * w3[h];
  }
  p += __shfl_xor(p, 16, 32);
  p += __shfl_xor(p, 8, 32);
  p += __shfl_xor(p, 4, 32);
  p += __shfl_xor(p, 2, 32);
  p += __shfl_xor(p, 1, 32);
  if (hb == 0) attn[t0 + sp] = p + b3[0];
}

// ---------------------------------------------------------------------------
// g[s] = [e[start], e[end], span_sum]; also writes gkg (k-grouped bf16)
// ---------------------------------------------------------------------------
__global__ __launch_bounds__(256) void k_spans(
    const float* __restrict__ e, const float* __restrict__ attn,
    const int* __restrict__ sstart, const int* __restrict__ swidth,
    float* __restrict__ g, u16* __restrict__ gkg) {
  const int s = blockIdx.x;
  int st = sstart[s];
  int en = st + swidth[s];
  if (en > 2047) en = 2047;
  if (en < 0) en = 0;
  const int tid = threadIdx.x;
  for (int d = tid; d < 768; d += 256) {
    float v0 = e[(size_t)st*768 + d];
    float v1 = e[(size_t)en*768 + d];
    float acc = 0.f;
    for (int t = st; t <= en; ++t) acc += e[(size_t)t*768 + d] * attn[t];
    g[s*2304 + d]        = v0;
    g[s*2304 + 768 + d]  = v1;
    g[s*2304 + 1536 + d] = acc;
    int c0 = d, c1 = 768 + d, c2 = 1536 + d;
    gkg[((size_t)(c0>>3)*256 + s)*8 + (c0&7)] = f2bf(v0);
    gkg[((size_t)(c1>>3)*256 + s)*8 + (c1&7)] = f2bf(v1);
    gkg[((size_t)(c2>>3)*256 + s)*8 + (c2&7)] = f2bf(acc);
  }
}

// ---------------------------------------------------------------------------
// span layer1 (split-bf16 MFMA GEMM, split-K x6): raw partials
// ---------------------------------------------------------------------------
__global__ __launch_bounds__(128) void k_span1(
    const float* __restrict__ g, const u16* __restrict__ Wh,
    const u16* __restrict__ Wl, float* __restrict__ pp) {
  __shared__ u16 lXh[16*64], lXl[16*64], lWh[160*64], lWl[160*64];
  const int tid = threadIdx.x, lane = tid & 63;
  const int wh = tid >> 6;
  const int m0 = blockIdx.x * 16;
  const int n0 = blockIdx.y * 160;
  const int z  = blockIdx.z;
  f32x4 acc[5] = {};
  for (int e0 = z*384; e0 < (z+1)*384; e0 += 64) {
    {
      int r = tid >> 3, ec = tid & 7;
      const float* src = g + (size_t)(m0 + r)*2304 + e0 + ec*8;
      float4 x0 = *(const float4*)src, x1 = *(const float4*)(src + 4);
      float xs[8] = {x0.x,x0.y,x0.z,x0.w,x1.x,x1.y,x1.z,x1.w};
      u16 hb[8], lb[8];
#pragma unroll
      for (int q = 0; q < 8; ++q) splitbf(xs[q], hb[q], lb[q]);
      int off = (r*128 + ec*16) ^ ((r & 7) << 4);
      *(uint4*)((char*)lXh + off) = make_uint4(
        (u32)hb[0]|((u32)hb[1]<<16), (u32)hb[2]|((u32)hb[3]<<16),
        (u32)hb[4]|((u32)hb[5]<<16), (u32)hb[6]|((u32)hb[7]<<16));
      *(uint4*)((char*)lXl + off) = make_uint4(
        (u32)lb[0]|((u32)lb[1]<<16), (u32)lb[2]|((u32)lb[3]<<16),
        (u32)lb[4]|((u32)lb[5]<<16), (u32)lb[6]|((u32)lb[7]<<16));
    }
#pragma unroll
    for (int t = 0; t < 10; ++t) {
      int c = tid + t*128;
      int h = c >> 3, ec = c & 7;
      int off = (h*128 + ec*16) ^ ((h & 7) << 4);
      *(uint4*)((char*)lWh + off) = *(const uint4*)(Wh + (size_t)(n0 + h)*2304 + e0 + ec*8);
      *(uint4*)((char*)lWl + off) = *(const uint4*)(Wl + (size_t)(n0 + h)*2304 + e0 + ec*8);
    }
    __syncthreads();
#pragma unroll
    for (int ks = 0; ks < 2; ++ks) {
      int eb = ks*64 + ((lane >> 4) << 4);
      int ar = lane & 15;
      bf16x8 Ah = *(const bf16x8*)((const char*)lXh + ((ar*128 + eb) ^ ((ar & 7) << 4)));
      bf16x8 Al = *(const bf16x8*)((const char*)lXl + ((ar*128 + eb) ^ ((ar & 7) << 4)));
#pragma unroll
      for (int t = 0; t < 5; ++t) {
        int br = wh*80 + t*16 + (lane & 15);
        bf16x8 Bh = *(const bf16x8*)((const char*)lWh + ((br*128 + eb) ^ ((br & 7) << 4)));
        bf16x8 Bl = *(const bf16x8*)((const char*)lWl + ((br*128 + eb) ^ ((br & 7) << 4)));
        acc[t] = __builtin_amdgcn_mfma_f32_16x16x32_bf16(Ah, Bh, acc[t], 0, 0, 0);
        acc[t] = __builtin_amdgcn_mfma_f32_16x16x32_bf16(Al, Bh, acc[t], 0, 0, 0);
        acc[t] = __builtin_amdgcn_mfma_f32_16x16x32_bf16(Ah, Bl, acc[t], 0, 0, 0);
      }
    }
    __syncthreads();
  }
#pragma unroll
  for (int t = 0; t < 5; ++t) {
    int nc = n0 + wh*80 + t*16 + (lane & 15);
#pragma unroll
    for (int r = 0; r < 4; ++r) {
      int m = m0 + ((lane >> 4) << 2) + r;
      pp[((size_t)z*256 + m)*480 + nc] = acc[t][r];
    }
  }
}

// ---------------------------------------------------------------------------
// span reduce + layers 2+3 (merged)
// ---------------------------------------------------------------------------
__global__ __launch_bounds__(256) void k_span2r(
    const float* __restrict__ pp, const float* __restrict__ mb1,
    const float* __restrict__ W2p, const float* __restrict__ b2,
    const float* __restrict__ w3, const float* __restrict__ b3,
    float* __restrict__ hi, float* __restrict__ hj, float* __restrict__ mo) {
  __shared__ float hs[8][160];
  const int tid = threadIdx.x;
  const int s0 = blockIdx.x * 8;
  for (int idx = tid; idx < 3840; idx += 256) {
    int mr = idx / 480, n = idx - mr * 480;
    int m = s0 + mr;
    float s = 0.f;
#pragma unroll
    for (int z = 0; z < 6; ++z) s += pp[((size_t)z*256 + m)*480 + n];
    if (n < 160)      hs[mr][n] = (n < 150) ? fmaxf(s + mb1[n], 0.f) : 0.f;
    else if (n < 320) hi[m*160 + n - 160] = s;
    else              hj[m*160 + n - 320] = s;
  }
  __syncthreads();
  const int sp = tid >> 5, hb = tid & 31;
  float a2[5] = {0.f,0.f,0.f,0.f,0.f};
  for (int k = 0; k < 150; ++k) {
    float x = hs[sp][k];
#pragma unroll
    for (int q = 0; q < 5; ++q) a2[q] = fmaf(x, W2p[k*160 + hb + 32*q], a2[q]);
  }
  float p = 0.f;
#pragma unroll
  for (int q = 0; q < 5; ++q) {
    int h = hb + 32*q;
    if (h < 150) p += fmaxf(a2[q] + b2[h], 0.f) * w3[h];
  }
  p += __shfl_xor(p, 16, 32);
  p += __shfl_xor(p, 8, 32);
  p += __shfl_xor(p, 4, 32);
  p += __shfl_xor(p, 2, 32);
  p += __shfl_xor(p, 1, 32);
  if (hb == 0) mo[s0 + sp] = p + b3[0];
}

// ---------------------------------------------------------------------------
// k_hij8: fused big einsum + pairwise MLP. ONE block per i (256 blocks,
// 1024 threads = 16 waves as wj(8) x wh(2); wave tile 32j x 80h, j-span 256).
// 4 waves/SIMD (vs 2 in k_hij7) to hide the per-wave serial chain
// (ds_read -> MFMA -> loads -> cvt -> ds_write -> barrier).
// A GLOBAL->VGPR from gkg; B' (g[i].*Wc) dbuf LDS, reg-staged cvt;
// single raw s_barrier + lgkmcnt(0)-only wait per chunk (counted vmcnt).
// LDS: B' dbuf 2x20480 @0; then h1' [20kg][256j][8] @0 (80K);
//      B2 @81920 (20K); red @102400. Total 104448.
// ---------------------------------------------------------------------------
__global__ __launch_bounds__(1024, 1) void k_hij8(
    const float* __restrict__ g, const u16* __restrict__ gkg,
    const u16* __restrict__ Wckg, const float* __restrict__ hi,
    const float* __restrict__ hj, const float* __restrict__ pb1p,
    const u16* __restrict__ W2kg, const float* __restrict__ pb2p,
    const float* __restrict__ w3p, const float* __restrict__ pb3,
    const float* __restrict__ mv, float* __restrict__ out) {
  __shared__ __align__(16) char smem[104448];
  const int tid = threadIdx.x, lane = tid & 63, w = tid >> 6;
  const int wj = w & 7, wh = w >> 3;
  const int i = blockIdx.x;
  const float* grow = g + (size_t)i * 2304;

  f32x4 acc[2][5] = {};
  bf16x8 afC[4];
  uint4 wcR[2];
  float4 gA[2], gB[2];

  // A fragment base: granule (kg, j) at ((t*8+kg)*256 + j)*8 elems
  const u16* pA = gkg + (((lane >> 4) * 256) + wj * 32 + (lane & 15)) * 8;
  const int ep0 = (tid / 160) * 8;
  const int ep1 = ((tid + 1024) / 160) * 8;
  const int bB = (((lane >> 4) * 160) + wh * 80 + (lane & 15)) * 16;

  auto loadA = [&](int t) {
    const u16* p = pA + (size_t)t * 16384;
#pragma unroll
    for (int ks = 0; ks < 2; ++ks)
#pragma unroll
      for (int q = 0; q < 2; ++q)
        afC[ks * 2 + q] = *(const bf16x8*)(p + ks * 8192 + q * 128);
  };
  auto loadB = [&](int t) {
    const u16* wp = Wckg + (size_t)t * 10240;
    const float* gp = grow + t * 64;
    wcR[0] = *(const uint4*)(wp + (size_t)tid * 8);
    gA[0] = *(const float4*)(gp + ep0); gB[0] = *(const float4*)(gp + ep0 + 4);
    if (tid < 256) {
      wcR[1] = *(const uint4*)(wp + (size_t)(tid + 1024) * 8);
      gA[1] = *(const float4*)(gp + ep1); gB[1] = *(const float4*)(gp + ep1 + 4);
    }
  };
  auto writeB = [&](int buf) {
    char* base = smem + buf * 20480;
    {
      uint4 v = wcR[0]; float4 ga = gA[0], gb = gB[0];
      uint4 r;
      r.x = cvtpk(bflo(v.x) * ga.x, bfhi(v.x) * ga.y);
      r.y = cvtpk(bflo(v.y) * ga.z, bfhi(v.y) * ga.w);
      r.z = cvtpk(bflo(v.z) * gb.x, bfhi(v.z) * gb.y);
      r.w = cvtpk(bflo(v.w) * gb.z, bfhi(v.w) * gb.w);
      *(uint4*)(base + tid * 16) = r;
    }
    if (tid < 256) {
      uint4 v = wcR[1]; float4 ga = gA[1], gb = gB[1];
      uint4 r;
      r.x = cvtpk(bflo(v.x) * ga.x, bfhi(v.x) * ga.y);
      r.y = cvtpk(bflo(v.y) * ga.z, bfhi(v.y) * ga.w);
      r.z = cvtpk(bflo(v.z) * gb.x, bfhi(v.z) * gb.y);
      r.w = cvtpk(bflo(v.w) * gb.z, bfhi(v.w) * gb.w);
      *(uint4*)(base + (tid + 1024) * 16) = r;
    }
  };

  // prologue: loadB first (older) so writeB's wait leaves loadA outstanding
  loadB(0);
  loadA(0);
  writeB(0);
  asm volatile("s_waitcnt lgkmcnt(0)" ::: "memory");
  __builtin_amdgcn_s_barrier();
  __builtin_amdgcn_sched_barrier(0);

  for (int t = 0; t < 36; ++t) {
    const int buf = t & 1;
    if (t < 35) loadB(t + 1);
    const char* Bb = smem + buf * 20480;
    __builtin_amdgcn_s_setprio(1);
#pragma unroll
    for (int ks = 0; ks < 2; ++ks) {
#pragma unroll
      for (int u = 0; u < 5; ++u) {
        bf16x8 bfr = *(const bf16x8*)(Bb + bB + ks * 10240 + u * 256);
#pragma unroll
        for (int q = 0; q < 2; ++q)
          acc[q][u] = __builtin_amdgcn_mfma_f32_16x16x32_bf16(
              afC[ks * 2 + q], bfr, acc[q][u], 0, 0, 0);
      }
    }
    __builtin_amdgcn_s_setprio(0);
    if (t < 35) { loadA(t + 1); writeB(buf ^ 1); }
    // this wave's ds ops only; global loads legally span the barrier
    asm volatile("s_waitcnt lgkmcnt(0)" ::: "memory");
    __builtin_amdgcn_s_barrier();
    __builtin_amdgcn_sched_barrier(0);
  }

  // ---- epilogue1: h1 = relu(hij + hi + hj + pb1) -> LDS bf16 [20][256][8] --
  {
    float hib[5];
#pragma unroll
    for (int u = 0; u < 5; ++u) {
      int h = wh * 80 + u * 16 + (lane & 15);
      hib[u] = hi[i * 160 + h] + pb1p[h];
    }
#pragma unroll
    for (int q = 0; q < 2; ++q) {
      int jl = wj * 32 + q * 16 + ((lane >> 4) << 2);
#pragma unroll
      for (int r = 0; r < 4; ++r) {
        const float* hjr = hj + (size_t)(jl + r) * 160;
#pragma unroll
        for (int u = 0; u < 5; ++u) {
          int h = wh * 80 + u * 16 + (lane & 15);
          float v = fmaxf(acc[q][u][r] + hib[u] + hjr[h], 0.f);
          *(u16*)(smem + ((h >> 3) * 256 + jl + r) * 16 + (h & 7) * 2) = f2bf(v);
        }
      }
    }
  }
  __syncthreads();

  // ---- GEMM2: h2 = h1' @ W2 (K=160), 3 chunks (8,8,4 kgrps) ----
  f32x4 acc2[2][5] = {};
  for (int c = 0; c < 3; ++c) {
    const int G64 = (c < 2) ? 20 : 10;
    for (int g0 = w; g0 < G64; g0 += 16) {
      const u16* src = W2kg + ((size_t)c * 1280 + g0 * 64 + lane) * 8;
      gload_lds16(src, smem + 81920 + g0 * 1024);
    }
    __syncthreads();
    const int nks = (c < 2) ? 2 : 1;
    for (int ks = 0; ks < nks; ++ks) {
      const int kl = ks * 4 + (lane >> 4);
      bf16x8 af2[2];
#pragma unroll
      for (int q = 0; q < 2; ++q)
        af2[q] = *(const bf16x8*)(smem + ((c * 8 + kl) * 256 + wj * 32 + q * 16 + (lane & 15)) * 16);
#pragma unroll
      for (int u = 0; u < 5; ++u) {
        bf16x8 b2 = *(const bf16x8*)(smem + 81920 + (kl * 160 + wh * 80 + u * 16 + (lane & 15)) * 16);
#pragma unroll
        for (int q = 0; q < 2; ++q)
          acc2[q][u] = __builtin_amdgcn_mfma_f32_16x16x32_bf16(af2[q], b2, acc2[q][u], 0, 0, 0);
      }
    }
    __syncthreads();
  }

  // ---- epilogue2: s = relu(h2 + pb2).w3 ; out = clip((mi+mj+s)/3) ----
  {
    float w3v[5], b2v[5];
#pragma unroll
    for (int u = 0; u < 5; ++u) {
      int h2 = wh * 80 + u * 16 + (lane & 15);
      w3v[u] = w3p[h2]; b2v[u] = pb2p[h2];
    }
#pragma unroll
    for (int q = 0; q < 2; ++q) {
#pragma unroll
      for (int r = 0; r < 4; ++r) {
        float sp = 0.f;
#pragma unroll
        for (int u = 0; u < 5; ++u)
          sp += fmaxf(acc2[q][u][r] + b2v[u], 0.f) * w3v[u];
        sp += __shfl_xor(sp, 1);
        sp += __shfl_xor(sp, 2);
        sp += __shfl_xor(sp, 4);
        sp += __shfl_xor(sp, 8);
        if ((lane & 15) == 0) {
          int jl = wj * 32 + q * 16 + ((lane >> 4) << 2) + r;
          *(float*)(smem + 102400 + (jl * 2 + wh) * 4) = sp;
        }
      }
    }
  }
  __syncthreads();
  if (tid < 256) {
    float s = *(const float*)(smem + 102400 + tid * 8) +
              *(const float*)(smem + 102400 + tid * 8 + 4) + pb3[0];
    float v = (mv[i] + mv[tid] + s) * (1.f / 3.f);
    out[i * 256 + tid] = fminf(fmaxf(v, 0.f), 1.f);
  }
}

// ---------------------------------------------------------------------------
extern "C" void kernel_launch(void* const* d_in, const int* in_sizes, int n_in,
                              void* d_out, int out_size, void* d_ws, size_t ws_size,
                              hipStream_t stream) {
  (void)in_sizes; (void)n_in; (void)out_size; (void)ws_size;
  const float* e    = (const float*)d_in[0];
  const int*   sst  = (const int*)d_in[1];
  const int*   swd  = (const int*)d_in[2];
  const float* aW1  = (const float*)d_in[3];
  const float* ab1  = (const float*)d_in[4];
  const float* aW2  = (const float*)d_in[5];
  const float* ab2  = (const float*)d_in[6];
  const float* aW3  = (const float*)d_in[7];
  const float* ab3  = (const float*)d_in[8];
  const float* mW1  = (const float*)d_in[9];
  const float* mb1  = (const float*)d_in[10];
  const float* mW2  = (const float*)d_in[11];
  const float* mb2  = (const float*)d_in[12];
  const float* mW3  = (const float*)d_in[13];
  const float* mb3  = (const float*)d_in[14];
  const float* pW1  = (const float*)d_in[15];
  const float* pb1  = (const float*)d_in[16];
  const float* pW2  = (const float*)d_in[17];
  const float* pb2  = (const float*)d_in[18];
  const float* pW3  = (const float*)d_in[19];
  const float* pb3  = (const float*)d_in[20];
  float* out = (float*)d_out;

  char* ws = (char*)d_ws;
  size_t off = 0;
  auto alloc = [&](size_t bytes) -> char* {
    char* p = ws + off;
    off += (bytes + 255) & ~(size_t)255;
    return p;
  };
  float* attn  = (float*)alloc(2048ULL*4);
  float* g     = (float*)alloc(256ULL*2304*4);
  float* hi    = (float*)alloc(256ULL*160*4);
  float* hj    = (float*)alloc(256ULL*160*4);
  float* mv    = (float*)alloc(256ULL*4);
  float* h1p   = (float*)alloc(4ULL*2048*160*4);
  float* pp    = (float*)alloc(6ULL*256*480*4);
  u16*   aW1Th = (u16*)alloc(160ULL*768*2);
  u16*   aW1Tl = (u16*)alloc(160ULL*768*2);
  u16*   Wcath = (u16*)alloc(480ULL*2304*2);
  u16*   Wcatl = (u16*)alloc(480ULL*2304*2);
  float* aW2p  = (float*)alloc(152ULL*160*4);
  float* mW2p  = (float*)alloc(152ULL*160*4);
  u16*   gkg   = (u16*)alloc(288ULL*256*8*2);
  u16*   Wckg  = (u16*)alloc(288ULL*160*8*2);
  u16*   W2kg  = (u16*)alloc(24ULL*1280*2);
  float* pb1p  = (float*)alloc(160ULL*4);
  float* pb2p  = (float*)alloc(160ULL*4);
  float* w3p   = (float*)alloc(160ULL*4);

  k_prepT<<<dim3(36, 6), 256, 0, stream>>>(mW1, pW1, aW1, aW2, mW2, pW2,
                                           pb1, pb2, pW3,
                                           Wcath, Wcatl, aW1Th, aW1Tl, Wckg,
                                           aW2p, mW2p, W2kg, pb1p, pb2p, w3p);
  k_attn1<<<dim3(64, 4), 256, 0, stream>>>(e, aW1Th, aW1Tl, h1p);
  k_attn2<<<256, 256, 0, stream>>>(h1p, aW2p, ab1, ab2, aW3, ab3, attn);
  k_spans<<<256, 256, 0, stream>>>(e, attn, sst, swd, g, gkg);
  k_span1<<<dim3(16, 3, 6), 128, 0, stream>>>(g, Wcath, Wcatl, pp);
  k_span2r<<<32, 256, 0, stream>>>(pp, mb1, mW2p, mb2, mW3, mb3, hi, hj, mv);
  k_hij8<<<256, 1024, 0, stream>>>(g, gkg, Wckg, hi, hj, pb1p,
                                   W2kg, pb2p, w3p, pb3, mv, out);
}